// Round 9
// baseline (878.322 us; speedup 1.0000x reference)
//
#include <hip/hip_runtime.h>

#define E_      262144
#define NNODES  32768
#define L_      2

typedef __attribute__((ext_vector_type(8))) short  bf16x8;
typedef __attribute__((ext_vector_type(4))) float  f32x4;

__device__ __forceinline__ float bf2f(unsigned short u) {
    union { unsigned int i; float f; } v; v.i = ((unsigned int)u) << 16; return v.f;
}
__device__ __forceinline__ unsigned short f2bf(float f) {
    union { float f; unsigned int i; } v; v.f = f;
    unsigned int r = v.i + 0x7FFFu + ((v.i >> 16) & 1u);   // round-nearest-even
    return (unsigned short)(r >> 16);
}

// combined fp32->bf16 for nodes + edge_attr
__global__ __launch_bounds__(256)
void k_cvt2(const float* __restrict__ a, unsigned short* __restrict__ oa, int n4a,
            const float* __restrict__ b, unsigned short* __restrict__ ob, int n4b)
{
    int i = blockIdx.x * 256 + threadIdx.x;
    if (i < n4a) {
        float4 v = reinterpret_cast<const float4*>(a)[i];
        ushort4 o; o.x = f2bf(v.x); o.y = f2bf(v.y); o.z = f2bf(v.z); o.w = f2bf(v.w);
        reinterpret_cast<ushort4*>(oa)[i] = o;
    } else if (i < n4a + n4b) {
        int j = i - n4a;
        float4 v = reinterpret_cast<const float4*>(b)[j];
        ushort4 o; o.x = f2bf(v.x); o.y = f2bf(v.y); o.z = f2bf(v.z); o.w = f2bf(v.w);
        reinterpret_cast<ushort4*>(ob)[j] = o;
    }
}

// batched weight transpose: 13 matrices in one dispatch. [K][N] fp32 -> [N][K] bf16
struct TD  { const float* s; unsigned short* d; int off; int K; int nsh; };
struct TDA { TD v[13]; int total; };

__global__ __launch_bounds__(256)
void k_transpose_all(TDA t)
{
    int idx = blockIdx.x * 256 + threadIdx.x;
    if (idx >= t.total) return;
    int j = 0;
#pragma unroll
    for (int m = 1; m < 13; ++m) if (idx >= t.v[m].off) j = m;
    const TD& td = t.v[j];
    int local = idx - td.off;
    int k = local >> td.nsh;
    int n = local & ((1 << td.nsh) - 1);
    td.d[(size_t)n * td.K + k] = f2bf(td.s[local]);
}

// ---------------------------------------------------------------------------
// FUSED 3-stage edge MLP, direct-from-global operands (no staging, 3 barriers).
// Per block: 64 edges x 128 cols, 4 waves (2x2); wave frag rows = (lane&15),
// k-slot = (lane>>4)*8 elems. A-frags (gathered node rows / eattr rows) and
// B-frags (weight rows, L2-hot: 32-96KB shared by all 4096 blocks) are loaded
// per-lane directly from global -- the wave covers 16 rows x 64B per frag.
// Only the h1/h2 handoff H lives in LDS (16KB -> occupancy VGPR-limited).
//   h1 = relu(concat(nodes[src],eattr,nodes[dst]) @ W0 + b0)   (12 ksteps)
//   h2 = relu(h1 @ W1 + b1)   (4 ksteps, A from H)
//   m  = h2 @ W2 + b2         (4 ksteps, A from H)
//   LNEPI=0: out[e]=m;   LNEPI=1: out[e]=LN(eattr[e]+m)*g+b
// ---------------------------------------------------------------------------
template<bool LNEPI>
__global__ __launch_bounds__(256, 4)
void fused_mlp3(const unsigned short* __restrict__ nodes,   // [NNODES][128]
                const unsigned short* __restrict__ eattr,   // [E][128]
                const int*            __restrict__ ei,      // [2][E]
                const unsigned short* __restrict__ W0T,     // [128][384]
                const unsigned short* __restrict__ W1T,     // [128][128]
                const unsigned short* __restrict__ W2T,     // [128][128]
                const float* __restrict__ b0, const float* __restrict__ b1,
                const float* __restrict__ b2,
                const float* __restrict__ g,  const float* __restrict__ bb,
                unsigned short* __restrict__ out)           // [E][128]
{
    __shared__ unsigned short H[64 * 128];   // 16KB: h1 then h2
    char* Hc = (char*)H;

    const int lane = threadIdx.x & 63;
    const int w    = threadIdx.x >> 6;
    const int wr   = w >> 1, wc = w & 1;
    const int m0   = blockIdx.x * 64;
    const int koff = (lane >> 4) * 8;        // k-slot (elems) within 32-k chunk
    const int arow = lane & 15;              // frag row within 16

    // per-lane gather bases (rows fixed for the whole kernel)
    const unsigned short *pAs[2], *pAe[2], *pAd[2];
#pragma unroll
    for (int m = 0; m < 2; ++m) {
        int e = m0 + wr * 32 + m * 16 + arow;
        pAs[m] = nodes + (size_t)ei[e]      * 128 + koff;
        pAd[m] = nodes + (size_t)ei[E_ + e] * 128 + koff;
        pAe[m] = eattr + (size_t)e          * 128 + koff;
    }
    const size_t brow = wc * 64 + (lane & 15);   // +n*16 added per frag

    f32x4 acc[2][4];
    auto zacc = [&]() {
#pragma unroll
        for (int m = 0; m < 2; ++m)
#pragma unroll
            for (int n = 0; n < 4; ++n) acc[m][n] = (f32x4){0.f, 0.f, 0.f, 0.f};
    };

    // write acc (+bias, relu) -> H [64 rows][256B], XOR-swizzled rows
    auto towrite = [&](const float* bias) {
#pragma unroll
        for (int n = 0; n < 4; ++n) {
            int cg = wc * 64 + n * 16 + (lane & 15);
            float bi = bias[cg];
#pragma unroll
            for (int m = 0; m < 2; ++m) {
#pragma unroll
                for (int j = 0; j < 4; ++j) {
                    int rg = wr * 32 + m * 16 + (lane >> 4) * 4 + j;
                    float v = fmaxf(acc[m][n][j] + bi, 0.f);
                    *(unsigned short*)(Hc + rg * 256 + ((2 * cg) ^ ((rg & 7) << 4))) = f2bf(v);
                }
            }
        }
    };

    // H-phase mma: A from LDS H, B direct from global WT (K=128)
    auto phaseH = [&](const unsigned short* WT) {
        zacc();
#pragma unroll
        for (int ks = 0; ks < 4; ++ks) {
            bf16x8 a[2], b[4];
#pragma unroll
            for (int m = 0; m < 2; ++m) {
                int row = wr * 32 + m * 16 + arow;
                a[m] = *reinterpret_cast<const bf16x8*>(
                    Hc + row * 256 + ((ks * 64 + (lane >> 4) * 16) ^ ((row & 7) << 4)));
            }
#pragma unroll
            for (int n = 0; n < 4; ++n)
                b[n] = *reinterpret_cast<const bf16x8*>(
                    WT + (brow + n * 16) * 128 + koff + ks * 32);
#pragma unroll
            for (int m = 0; m < 2; ++m)
#pragma unroll
                for (int n = 0; n < 4; ++n)
                    acc[m][n] = __builtin_amdgcn_mfma_f32_16x16x32_bf16(a[m], b[n], acc[m][n], 0, 0, 0);
        }
    };

    // ======== phase 1: h1 = relu(X @ W0 + b0), K=384, direct loads ========
    zacc();
#pragma unroll
    for (int ks = 0; ks < 12; ++ks) {
        bf16x8 a[2], b[4];
#pragma unroll
        for (int m = 0; m < 2; ++m) {
            const unsigned short* p = (ks < 4 ? pAs[m] : (ks < 8 ? pAe[m] : pAd[m]));
            a[m] = *reinterpret_cast<const bf16x8*>(p + (ks & 3) * 32);
        }
#pragma unroll
        for (int n = 0; n < 4; ++n)
            b[n] = *reinterpret_cast<const bf16x8*>(
                W0T + (brow + n * 16) * 384 + koff + ks * 32);
#pragma unroll
        for (int m = 0; m < 2; ++m)
#pragma unroll
            for (int n = 0; n < 4; ++n)
                acc[m][n] = __builtin_amdgcn_mfma_f32_16x16x32_bf16(a[m], b[n], acc[m][n], 0, 0, 0);
    }
    towrite(b0);
    __syncthreads();            // h1 visible
    // ======== phase 2: h2 = relu(h1 @ W1 + b1) ========
    phaseH(W1T);
    __syncthreads();            // all h1 reads done
    towrite(b1);
    __syncthreads();            // h2 visible
    // ======== phase 3: m = h2 @ W2 + b2 ========
    phaseH(W2T);

    // ======== epilogue ========
    if (!LNEPI) {
#pragma unroll
        for (int n = 0; n < 4; ++n) {
            int cg = wc * 64 + n * 16 + (lane & 15);
            float bi = b2[cg];
#pragma unroll
            for (int m = 0; m < 2; ++m) {
                int rg = m0 + wr * 32 + m * 16 + (lane >> 4) * 4;
                unsigned short* cp = out + (size_t)rg * 128 + cg;
#pragma unroll
                for (int j = 0; j < 4; ++j)
                    cp[(size_t)j * 128] = f2bf(acc[m][n][j] + bi);
            }
        }
    } else {
        // residual + LayerNorm fused. vals = m + b2 + eattr.
#pragma unroll
        for (int n = 0; n < 4; ++n) {
            int cg = wc * 64 + n * 16 + (lane & 15);
            float bi = b2[cg];
#pragma unroll
            for (int m = 0; m < 2; ++m) {
#pragma unroll
                for (int j = 0; j < 4; ++j) {
                    int rg = m0 + wr * 32 + m * 16 + (lane >> 4) * 4 + j;
                    acc[m][n][j] += bi + bf2f(eattr[(size_t)rg * 128 + cg]);
                }
            }
        }
        __syncthreads();                  // phase-3 H reads done; H reusable
        float* ps = (float*)Hc;           // [2][64] row sums
        float* pq = ps + 128;             // [2][64] row sumsq
#pragma unroll
        for (int m = 0; m < 2; ++m) {
#pragma unroll
            for (int j = 0; j < 4; ++j) {
                float s = 0.f, q = 0.f;
#pragma unroll
                for (int n = 0; n < 4; ++n) {
                    float v = acc[m][n][j];
                    s += v; q += v * v;
                }
#pragma unroll
                for (int msk = 1; msk < 16; msk <<= 1) {
                    s += __shfl_xor(s, msk);
                    q += __shfl_xor(q, msk);
                }
                if ((lane & 15) == 0) {
                    int rl = wr * 32 + m * 16 + (lane >> 4) * 4 + j;
                    ps[wc * 64 + rl] = s;
                    pq[wc * 64 + rl] = q;
                }
            }
        }
        __syncthreads();
#pragma unroll
        for (int m = 0; m < 2; ++m) {
#pragma unroll
            for (int j = 0; j < 4; ++j) {
                int rl = wr * 32 + m * 16 + (lane >> 4) * 4 + j;
                float S = ps[rl] + ps[64 + rl];
                float Q = pq[rl] + pq[64 + rl];
                float mean = S * (1.f / 128.f);
                float var  = Q * (1.f / 128.f) - mean * mean;
                float rs   = rsqrtf(var + 1e-5f);
                int rg = m0 + rl;
#pragma unroll
                for (int n = 0; n < 4; ++n) {
                    int cg = wc * 64 + n * 16 + (lane & 15);
                    out[(size_t)rg * 128 + cg] =
                        f2bf((acc[m][n][j] - mean) * rs * g[cg] + bb[cg]);
                }
            }
        }
    }
}

// ---------------------------------------------------------------------------
// FF GEMM, fully direct-from-global: no LDS, no barriers. 64x128 tile/block.
// ---------------------------------------------------------------------------
template<int K, int NTOT, bool RELU>
__global__ __launch_bounds__(256, 4)
void mlp_gemm_direct(const unsigned short* __restrict__ A,   // [M][K]
                     const unsigned short* __restrict__ WT,  // [NTOT][K]
                     const float* __restrict__ bias,
                     unsigned short* __restrict__ C)         // [M][NTOT]
{
    const int lane = threadIdx.x & 63;
    const int w    = threadIdx.x >> 6;
    const int wr   = w >> 1, wc = w & 1;
    const int m0   = blockIdx.x * 64;
    const int n0   = blockIdx.y * 128;
    const int koff = (lane >> 4) * 8;

    const unsigned short *pA[2], *pB[4];
#pragma unroll
    for (int m = 0; m < 2; ++m)
        pA[m] = A + (size_t)(m0 + wr * 32 + m * 16 + (lane & 15)) * K + koff;
#pragma unroll
    for (int n = 0; n < 4; ++n)
        pB[n] = WT + (size_t)(n0 + wc * 64 + n * 16 + (lane & 15)) * K + koff;

    f32x4 acc[2][4];
#pragma unroll
    for (int m = 0; m < 2; ++m)
#pragma unroll
        for (int n = 0; n < 4; ++n) acc[m][n] = (f32x4){0.f, 0.f, 0.f, 0.f};

#pragma unroll
    for (int ks = 0; ks < K / 32; ++ks) {
        bf16x8 a[2], b[4];
#pragma unroll
        for (int m = 0; m < 2; ++m)
            a[m] = *reinterpret_cast<const bf16x8*>(pA[m] + ks * 32);
#pragma unroll
        for (int n = 0; n < 4; ++n)
            b[n] = *reinterpret_cast<const bf16x8*>(pB[n] + ks * 32);
#pragma unroll
        for (int m = 0; m < 2; ++m)
#pragma unroll
            for (int n = 0; n < 4; ++n)
                acc[m][n] = __builtin_amdgcn_mfma_f32_16x16x32_bf16(a[m], b[n], acc[m][n], 0, 0, 0);
    }

#pragma unroll
    for (int n = 0; n < 4; ++n) {
        int colg = n0 + wc * 64 + n * 16 + (lane & 15);
        float bi = bias[colg];
#pragma unroll
        for (int m = 0; m < 2; ++m) {
            int rowg = m0 + wr * 32 + m * 16 + (lane >> 4) * 4;
            unsigned short* cp = C + (size_t)rowg * NTOT + colg;
#pragma unroll
            for (int j = 0; j < 4; ++j) {
                float r = acc[m][n][j] + bi;
                if (RELU) r = fmaxf(r, 0.f);
                cp[(size_t)j * NTOT] = f2bf(r);
            }
        }
    }
}

__global__ __launch_bounds__(256)
void k_deg(const int* __restrict__ ei, int* __restrict__ deg)
{
    int e = blockIdx.x * 256 + threadIdx.x;
    atomicAdd(&deg[ei[E_ + e]], 1);
}

// exclusive scan of deg[32768] -> off[32769]
__global__ __launch_bounds__(1024)
void k_scan(const int* __restrict__ deg, int* __restrict__ off)
{
    __shared__ int part[1024];
    const int t = threadIdx.x;
    const int base = t * 32;
    int loc[32];
    int s = 0;
#pragma unroll
    for (int i = 0; i < 32; ++i) { loc[i] = s; s += deg[base + i]; }
    part[t] = s;
    __syncthreads();
    for (int d = 1; d < 1024; d <<= 1) {
        int v = (t >= d) ? part[t - d] : 0;
        __syncthreads();
        part[t] += v;
        __syncthreads();
    }
    const int pre = (t == 0) ? 0 : part[t - 1];
#pragma unroll
    for (int i = 0; i < 32; ++i) off[base + i] = pre + loc[i];
    if (t == 1023) off[NNODES] = pre + s;
}

__global__ __launch_bounds__(256)
void k_bucket(const int* __restrict__ ei, int* __restrict__ cursor, int* __restrict__ elist)
{
    int e = blockIdx.x * 256 + threadIdx.x;
    int d = ei[E_ + e];
    int pos = atomicAdd(&cursor[d], 1);
    elist[pos] = e;
}

// Fused: agg = mean_{e in CSR[v]} m[e];  out = LN(nodes_in[v] + agg).
__global__ __launch_bounds__(256)
void k_aggln(const unsigned short* __restrict__ m,
             const int* __restrict__ off, const int* __restrict__ elist,
             const unsigned short* __restrict__ nodes_in,
             const float* __restrict__ g, const float* __restrict__ bb,
             unsigned short* __restrict__ nodes_out)
{
    const int v    = blockIdx.x * 4 + (threadIdx.x >> 6);
    const int lane = threadIdx.x & 63;
    const int c    = lane * 2;
    const int beg  = off[v], end = off[v + 1];

    float a0 = 0.f, a1 = 0.f;
    for (int i = beg; i < end; ++i) {
        int e = elist[i];
        unsigned int u = *reinterpret_cast<const unsigned int*>(m + (size_t)e * 128 + c);
        a0 += bf2f((unsigned short)(u & 0xffffu));
        a1 += bf2f((unsigned short)(u >> 16));
    }
    const float inv = 1.f / fmaxf((float)(end - beg), 1.f);
    const size_t o = (size_t)v * 128 + c;
    float x0 = bf2f(nodes_in[o])     + a0 * inv;
    float x1 = bf2f(nodes_in[o + 1]) + a1 * inv;

    float s = x0 + x1, sq = x0 * x0 + x1 * x1;
#pragma unroll
    for (int mm = 1; mm < 64; mm <<= 1) { s += __shfl_xor(s, mm); sq += __shfl_xor(sq, mm); }
    float mean = s * (1.f / 128.f);
    float var  = sq * (1.f / 128.f) - mean * mean;
    float rs   = rsqrtf(var + 1e-5f);
    nodes_out[o]     = f2bf((x0 - mean) * rs * g[c]     + bb[c]);
    nodes_out[o + 1] = f2bf((x1 - mean) * rs * g[c + 1] + bb[c + 1]);
}

// Fused residual + LayerNorm (bf16 residual). F32OUT: fp32 final output.
template<bool F32OUT>
__global__ __launch_bounds__(256)
void k_ln(const unsigned short* __restrict__ base,
          const unsigned short* __restrict__ res,
          const float* __restrict__ g, const float* __restrict__ bb,
          void* __restrict__ outp)
{
    int row  = blockIdx.x * 4 + (threadIdx.x >> 6);
    int lane = threadIdx.x & 63;
    int c    = lane * 2;
    size_t off = (size_t)row * 128 + c;

    float x0 = bf2f(base[off])     + bf2f(res[off]);
    float x1 = bf2f(base[off + 1]) + bf2f(res[off + 1]);
    float s = x0 + x1, sq = x0 * x0 + x1 * x1;
#pragma unroll
    for (int m = 1; m < 64; m <<= 1) { s += __shfl_xor(s, m); sq += __shfl_xor(sq, m); }
    float mean = s * (1.f / 128.f);
    float var  = sq * (1.f / 128.f) - mean * mean;
    float rs   = rsqrtf(var + 1e-5f);
    float y0 = (x0 - mean) * rs * g[c]     + bb[c];
    float y1 = (x1 - mean) * rs * g[c + 1] + bb[c + 1];
    if (F32OUT) {
        ((float*)outp)[off]     = y0;
        ((float*)outp)[off + 1] = y1;
    } else {
        ((unsigned short*)outp)[off]     = f2bf(y0);
        ((unsigned short*)outp)[off + 1] = f2bf(y1);
    }
}

// ---------------------------------------------------------------------------
extern "C" void kernel_launch(void* const* d_in, const int* in_sizes, int n_in,
                              void* d_out, int out_size, void* d_ws, size_t ws_size,
                              hipStream_t stream)
{
    const float* x      = (const float*)d_in[0];
    const int*   ei     = (const int*)d_in[1];
    const float* eat0   = (const float*)d_in[2];
    const float* msg_W0 = (const float*)d_in[3];
    const float* msg_b0 = (const float*)d_in[4];
    const float* msg_W1 = (const float*)d_in[5];
    const float* msg_b1 = (const float*)d_in[6];
    const float* msg_W2 = (const float*)d_in[7];
    const float* msg_b2 = (const float*)d_in[8];
    const float* n0g    = (const float*)d_in[9];
    const float* n0b    = (const float*)d_in[10];
    const float* ff_W0  = (const float*)d_in[11];
    const float* ff_b0  = (const float*)d_in[12];
    const float* ff_W1  = (const float*)d_in[13];
    const float* ff_b1  = (const float*)d_in[14];
    const float* n1g    = (const float*)d_in[15];
    const float* n1b    = (const float*)d_in[16];
    const float* e_W0   = (const float*)d_in[17];
    const float* e_b0   = (const float*)d_in[18];
    const float* e_W1   = (const float*)d_in[19];
    const float* e_b1   = (const float*)d_in[20];
    const float* e_W2   = (const float*)d_in[21];
    const float* e_b2   = (const float*)d_in[22];
    const float* eng    = (const float*)d_in[23];
    const float* enb    = (const float*)d_in[24];

    char* ws = (char*)d_ws;
    const size_t MB = (size_t)1 << 20;
    unsigned short* nodes = (unsigned short*)(ws);                 // 8 MB bf16
    unsigned short* edgec = (unsigned short*)(ws + 8 * MB);        // 64 MB bf16
    unsigned short* tmpA  = (unsigned short*)(ws + 72 * MB);       // 64 MB (msg out m)
    unsigned short* ffh   = (unsigned short*)(ws + 136 * MB);      // 32 MB (FF hidden)
    unsigned short* ffo   = tmpA;                                  // alias (phase-disjoint)
    unsigned short* wt    = (unsigned short*)(ws + 200 * MB);      // ~1 MB bf16
    int*            deg   = (int*)(ws + 202 * MB);                 // 128 KB
    int*            off   = (int*)(ws + 202 * MB + 256 * 1024);    // 128 KB + 4
    int*            cur   = (int*)(ws + 202 * MB + 512 * 1024);    // 128 KB
    int*            elist = (int*)(ws + 202 * MB + 768 * 1024);    // 1 MB

    // weight transpose targets (bf16 [N][K])
    unsigned short* p = wt;
    unsigned short *wt_m0[L_], *wt_m1[L_], *wt_m2[L_], *wt_f0[L_], *wt_f1[L_];
    for (int l = 0; l < L_; ++l) {
        wt_m0[l] = p; p += 384 * 128;
        wt_m1[l] = p; p += 128 * 128;
        wt_m2[l] = p; p += 128 * 128;
        wt_f0[l] = p; p += 128 * 512;
        wt_f1[l] = p; p += 512 * 128;
    }
    unsigned short* wt_e0 = p; p += 384 * 128;
    unsigned short* wt_e1 = p; p += 128 * 128;
    unsigned short* wt_e2 = p; p += 128 * 128;

    TDA tda; int toff = 0, ti = 0;
    auto addT = [&](const float* s, unsigned short* d, int K, int N) {
        tda.v[ti++] = TD{s, d, toff, K, (N == 512 ? 9 : 7)};
        toff += K * N;
    };
    for (int l = 0; l < L_; ++l) {
        addT(msg_W0 + l * 384 * 128, wt_m0[l], 384, 128);
        addT(msg_W1 + l * 128 * 128, wt_m1[l], 128, 128);
        addT(msg_W2 + l * 128 * 128, wt_m2[l], 128, 128);
        addT(ff_W0  + l * 128 * 512, wt_f0[l], 128, 512);
        addT(ff_W1  + l * 512 * 128, wt_f1[l], 512, 128);
    }
    addT(e_W0, wt_e0, 384, 128);   // layer-0 edge update only (layer-1's is dead code)
    addT(e_W1, wt_e1, 128, 128);
    addT(e_W2, wt_e2, 128, 128);
    tda.total = toff;
    k_transpose_all<<<(toff + 255) / 256, 256, 0, stream>>>(tda);

    const int n4a = NNODES * 128 / 4, n4b = E_ * 128 / 4;
    k_cvt2<<<(n4a + n4b + 255) / 256, 256, 0, stream>>>(x, nodes, n4a, eat0, edgec, n4b);

    // CSR build (once — edge_index constant across layers)
    hipMemsetAsync(deg, 0, NNODES * sizeof(int), stream);
    k_deg<<<E_ / 256, 256, 0, stream>>>(ei, deg);
    k_scan<<<1, 1024, 0, stream>>>(deg, off);
    hipMemcpyAsync(cur, off, NNODES * sizeof(int), hipMemcpyDeviceToDevice, stream);
    k_bucket<<<E_ / 256, 256, 0, stream>>>(ei, cur, elist);

    const dim3 gE(E_ / 64, 1), gN64(NNODES / 64, 1), gF0(NNODES / 64, 4);

    for (int l = 0; l < L_; ++l) {
        // --- fused message MLP (3 GEMMs, direct operands) -> m ---
        fused_mlp3<false><<<gE, 256, 0, stream>>>(nodes, edgec, ei,
            wt_m0[l], wt_m1[l], wt_m2[l],
            msg_b0 + l * 128, msg_b1 + l * 128, msg_b2 + l * 128,
            nullptr, nullptr, tmpA);
        k_aggln<<<NNODES / 4, 256, 0, stream>>>(tmpA, off, elist, nodes,
            n0g + l * 128, n0b + l * 128, nodes);
        // --- feedforward + LN (direct GEMMs, no LDS) ---
        mlp_gemm_direct<128, 512, true ><<<gF0, 256, 0, stream>>>(nodes, wt_f0[l], ff_b0 + l * 512, ffh);
        mlp_gemm_direct<512, 128, false><<<gN64, 256, 0, stream>>>(ffh, wt_f1[l], ff_b1 + l * 128, ffo);
        if (l == L_ - 1) {
            k_ln<true ><<<NNODES / 4, 256, 0, stream>>>(nodes, ffo, n1g + l * 128, n1b + l * 128, d_out);
        } else {
            k_ln<false><<<NNODES / 4, 256, 0, stream>>>(nodes, ffo, n1g + l * 128, n1b + l * 128, nodes);
        }
        // --- fused edge update incl. residual+LN (only layer 0; layer-1's is dead) ---
        if (l == 0) {
            fused_mlp3<true><<<gE, 256, 0, stream>>>(nodes, edgec, ei,
                wt_e0, wt_e1, wt_e2, e_b0, e_b1, e_b2, eng, enb, edgec);
        }
    }
}

// Round 10
// 481.677 us; speedup vs baseline: 1.8235x; 1.8235x over previous
//
#include <hip/hip_runtime.h>

#define E_      262144
#define NNODES  32768
#define L_      2

typedef __attribute__((ext_vector_type(8))) short  bf16x8;
typedef __attribute__((ext_vector_type(4))) float  f32x4;

typedef __attribute__((address_space(1))) const unsigned int gu32;
typedef __attribute__((address_space(3))) unsigned int       lu32;

__device__ __forceinline__ void gl16(const void* g, void* l) {
    // async global->LDS, 16B/lane; LDS dest = wave-uniform base + lane*16
    __builtin_amdgcn_global_load_lds((gu32*)g, (lu32*)l, 16, 0, 0);
}

__device__ __forceinline__ float bf2f(unsigned short u) {
    union { unsigned int i; float f; } v; v.i = ((unsigned int)u) << 16; return v.f;
}
__device__ __forceinline__ unsigned short f2bf(float f) {
    union { float f; unsigned int i; } v; v.f = f;
    unsigned int r = v.i + 0x7FFFu + ((v.i >> 16) & 1u);   // round-nearest-even
    return (unsigned short)(r >> 16);
}

// combined fp32->bf16 for nodes + edge_attr
__global__ __launch_bounds__(256)
void k_cvt2(const float* __restrict__ a, unsigned short* __restrict__ oa, int n4a,
            const float* __restrict__ b, unsigned short* __restrict__ ob, int n4b)
{
    int i = blockIdx.x * 256 + threadIdx.x;
    if (i < n4a) {
        float4 v = reinterpret_cast<const float4*>(a)[i];
        ushort4 o; o.x = f2bf(v.x); o.y = f2bf(v.y); o.z = f2bf(v.z); o.w = f2bf(v.w);
        reinterpret_cast<ushort4*>(oa)[i] = o;
    } else if (i < n4a + n4b) {
        int j = i - n4a;
        float4 v = reinterpret_cast<const float4*>(b)[j];
        ushort4 o; o.x = f2bf(v.x); o.y = f2bf(v.y); o.z = f2bf(v.z); o.w = f2bf(v.w);
        reinterpret_cast<ushort4*>(ob)[j] = o;
    }
}

// batched weight transpose: 13 matrices in one dispatch. [K][N] fp32 -> [N][K] bf16
struct TD  { const float* s; unsigned short* d; int off; int K; int nsh; };
struct TDA { TD v[13]; int total; };

__global__ __launch_bounds__(256)
void k_transpose_all(TDA t)
{
    int idx = blockIdx.x * 256 + threadIdx.x;
    if (idx >= t.total) return;
    int j = 0;
#pragma unroll
    for (int m = 1; m < 13; ++m) if (idx >= t.v[m].off) j = m;
    const TD& td = t.v[j];
    int local = idx - td.off;
    int k = local >> td.nsh;
    int n = local & ((1 << td.nsh) - 1);
    td.d[(size_t)n * td.K + k] = f2bf(td.s[local]);
}

// ---------------------------------------------------------------------------
// FUSED 3-stage edge MLP, BM=64, K-chunk-32 DOUBLE-BUFFER with COUNTED VMCNT
// (T4): per kstep  { stage(t+1, buf^1);  s_waitcnt vmcnt(3);  s_barrier;
//                    sched_barrier; mma(buf); sched_barrier; s_barrier }
// -- prefetch loads stay in flight across the barrier (never vmcnt(0) in the
// loop; R7's failure was __syncthreads' implicit full drain).
// Safety: vmcnt(N) is per-wave, but each wave waits its OWN current-buffer
// loads before the barrier, so after the barrier all staging for buf is
// complete. Trailing barrier keeps buf readers ahead of next overwrite.
// LDS: A dbuf 2x4KB + W dbuf 2x8KB + H 16KB = 40KB -> 4 blocks/CU.
//   h1 = relu(concat(nodes[src],eattr,nodes[dst]) @ W0 + b0)  (12 ksteps)
//   h2 = relu(h1 @ W1 + b1)  (4 ksteps);  m = h2 @ W2 + b2  (4 ksteps)
//   LNEPI=0: out[e]=m;  LNEPI=1: out[e]=LN(eattr[e]+m)*g+b
// ---------------------------------------------------------------------------
template<bool LNEPI>
__global__ __launch_bounds__(256, 4)
void fused_mlp3(const unsigned short* __restrict__ nodes,   // [NNODES][128]
                const unsigned short* __restrict__ eattr,   // [E][128]
                const int*            __restrict__ ei,      // [2][E]
                const unsigned short* __restrict__ W0T,     // [128][384]
                const unsigned short* __restrict__ W1T,     // [128][128]
                const unsigned short* __restrict__ W2T,     // [128][128]
                const float* __restrict__ b0, const float* __restrict__ b1,
                const float* __restrict__ b2,
                const float* __restrict__ g,  const float* __restrict__ bb,
                unsigned short* __restrict__ out)           // [E][128]
{
    __shared__ unsigned short S0[2][64 * 32];    //  8KB A-stage dbuf
    __shared__ unsigned short SB[2][128 * 32];   // 16KB W-stage dbuf / LN scratch
    __shared__ unsigned short H [64 * 128];      // 16KB h1 then h2

    const int tid  = threadIdx.x;
    const int lane = tid & 63;
    const int w    = tid >> 6;
    const int wr   = w >> 1, wc = w & 1;
    const int m0   = blockIdx.x * 64;

    const int l4   = lane >> 2;                                  // 0..15 row-in-issue
    const int soff = (((lane & 3) ^ ((l4 >> 1) & 3)) << 3);      // inverse-swz slot (elems)

    char* S0c = (char*)S0;
    char* SBc = (char*)SB;
    char* Hc  = (char*)H;

    // gather row pointers: 1 issue/wave covers 16 rows of 64B; 4 waves = 64 rows
    const int er = m0 + w * 16 + l4;
    const unsigned short* pS = nodes + (size_t)ei[er]      * 128 + soff;
    const unsigned short* pD = nodes + (size_t)ei[E_ + er] * 128 + soff;
    const unsigned short* pE = eattr + (size_t)er          * 128 + soff;

    f32x4 acc[2][4];
    auto zacc = [&]() {
#pragma unroll
        for (int m = 0; m < 2; ++m)
#pragma unroll
            for (int n = 0; n < 4; ++n) acc[m][n] = (f32x4){0.f, 0.f, 0.f, 0.f};
    };

    // ---- staging (K-chunk = 32 elems = 64B/row) ----
    auto stageA = [&](int t, int buf) {
        const unsigned short* p = (t < 4 ? pS : (t < 8 ? pE : pD)) + (t & 3) * 32;
        gl16(p, S0c + buf * 4096 + w * 1024);
    };
    auto stageW = [&](const unsigned short* WT, int Kr, int t, int buf) {
#pragma unroll
        for (int i = 0; i < 2; ++i)
            gl16(WT + (size_t)(w * 32 + i * 16 + l4) * Kr + t * 32 + soff,
                 SBc + buf * 8192 + w * 2048 + i * 1024);
    };

    const int q4 = (lane >> 4) << 4;    // 16B slot base within 64B row

    auto ldB = [&](int buf, bf16x8* b) {
#pragma unroll
        for (int n = 0; n < 4; ++n) {
            int row = wc * 64 + n * 16 + (lane & 15);
            b[n] = *reinterpret_cast<const bf16x8*>(
                SBc + buf * 8192 + row * 64 + (q4 ^ (((row >> 1) & 3) << 4)));
        }
    };

    auto mmaP1 = [&](int buf) {
        bf16x8 a[2], b[4];
        ldB(buf, b);
#pragma unroll
        for (int m = 0; m < 2; ++m) {
            int row = wr * 32 + m * 16 + (lane & 15);
            a[m] = *reinterpret_cast<const bf16x8*>(
                S0c + buf * 4096 + row * 64 + (q4 ^ (((row >> 1) & 3) << 4)));
        }
#pragma unroll
        for (int m = 0; m < 2; ++m)
#pragma unroll
            for (int n = 0; n < 4; ++n)
                acc[m][n] = __builtin_amdgcn_mfma_f32_16x16x32_bf16(a[m], b[n], acc[m][n], 0, 0, 0);
    };

    auto mmaH = [&](int t, int buf) {
        bf16x8 a[2], b[4];
        ldB(buf, b);
#pragma unroll
        for (int m = 0; m < 2; ++m) {
            int row = wr * 32 + m * 16 + (lane & 15);
            a[m] = *reinterpret_cast<const bf16x8*>(
                Hc + row * 256 + ((t * 64 + q4) ^ ((row & 7) << 4)));
        }
#pragma unroll
        for (int m = 0; m < 2; ++m)
#pragma unroll
            for (int n = 0; n < 4; ++n)
                acc[m][n] = __builtin_amdgcn_mfma_f32_16x16x32_bf16(a[m], b[n], acc[m][n], 0, 0, 0);
    };

    // ---- write activated acc -> H [64][128] bf16 (256B rows, swizzled) ----
    auto towrite = [&](const float* bias) {
#pragma unroll
        for (int n = 0; n < 4; ++n) {
            int cg = wc * 64 + n * 16 + (lane & 15);
            float bi = bias[cg];
#pragma unroll
            for (int m = 0; m < 2; ++m) {
#pragma unroll
                for (int j = 0; j < 4; ++j) {
                    int rg = wr * 32 + m * 16 + (lane >> 4) * 4 + j;
                    float v = fmaxf(acc[m][n][j] + bi, 0.f);
                    *(unsigned short*)(Hc + rg * 256 + ((2 * cg) ^ ((rg & 7) << 4))) = f2bf(v);
                }
            }
        }
    };

    // ========== phase 1: h1 = relu(X @ W0 + b0), 12 ksteps, counted vmcnt ====
    zacc();
    stageA(0, 0); stageW(W0T, 384, 0, 0);
#pragma unroll
    for (int t = 0; t < 12; ++t) {
        const int pb = t & 1;
        if (t < 11) {
            stageA(t + 1, pb ^ 1); stageW(W0T, 384, t + 1, pb ^ 1);
            asm volatile("s_waitcnt vmcnt(3)" ::: "memory");   // current-buf loads done
        } else {
            asm volatile("s_waitcnt vmcnt(0)" ::: "memory");
        }
        __builtin_amdgcn_s_barrier();          // all waves' staging for pb complete
        __builtin_amdgcn_sched_barrier(0);
        mmaP1(pb);
        __builtin_amdgcn_sched_barrier(0);
        __builtin_amdgcn_s_barrier();          // pb readers done before next overwrite
    }
    towrite(b0);
    __syncthreads();                            // h1 visible (drain ok: 0 in flight)
    // ========== phase 2: h2 = relu(h1 @ W1 + b1), 4 ksteps ====
    zacc();
    stageW(W1T, 128, 0, 0);
#pragma unroll
    for (int t = 0; t < 4; ++t) {
        const int pb = t & 1;
        if (t < 3) {
            stageW(W1T, 128, t + 1, pb ^ 1);
            asm volatile("s_waitcnt vmcnt(2)" ::: "memory");
        } else {
            asm volatile("s_waitcnt vmcnt(0)" ::: "memory");
        }
        __builtin_amdgcn_s_barrier();
        __builtin_amdgcn_sched_barrier(0);
        mmaH(t, pb);
        __builtin_amdgcn_sched_barrier(0);
        __builtin_amdgcn_s_barrier();
    }
    towrite(b1);                                // h2 over h1 (readers done at trailing barrier)
    __syncthreads();
    // ========== phase 3: m = h2 @ W2 + b2, 4 ksteps ====
    zacc();
    stageW(W2T, 128, 0, 0);
#pragma unroll
    for (int t = 0; t < 4; ++t) {
        const int pb = t & 1;
        if (t < 3) {
            stageW(W2T, 128, t + 1, pb ^ 1);
            asm volatile("s_waitcnt vmcnt(2)" ::: "memory");
        } else {
            asm volatile("s_waitcnt vmcnt(0)" ::: "memory");
        }
        __builtin_amdgcn_s_barrier();
        __builtin_amdgcn_sched_barrier(0);
        mmaH(t, pb);
        __builtin_amdgcn_sched_barrier(0);
        __builtin_amdgcn_s_barrier();
    }

    // ========== epilogue ==========
    if (!LNEPI) {
#pragma unroll
        for (int n = 0; n < 4; ++n) {
            int cg = wc * 64 + n * 16 + (lane & 15);
            float bi = b2[cg];
#pragma unroll
            for (int m = 0; m < 2; ++m) {
                int rg = m0 + wr * 32 + m * 16 + (lane >> 4) * 4;
                unsigned short* cp = out + (size_t)rg * 128 + cg;
#pragma unroll
                for (int j = 0; j < 4; ++j)
                    cp[(size_t)j * 128] = f2bf(acc[m][n][j] + bi);
            }
        }
    } else {
        // residual + LayerNorm fused. vals = m + b2 + eattr.
#pragma unroll
        for (int n = 0; n < 4; ++n) {
            int cg = wc * 64 + n * 16 + (lane & 15);
            float bi = b2[cg];
#pragma unroll
            for (int m = 0; m < 2; ++m) {
#pragma unroll
                for (int j = 0; j < 4; ++j) {
                    int rg = m0 + wr * 32 + m * 16 + (lane >> 4) * 4 + j;
                    acc[m][n][j] += bi + bf2f(eattr[(size_t)rg * 128 + cg]);
                }
            }
        }
        float* ps = (float*)SBc;          // [2][64] row sums   (SB reads done)
        float* pq = ps + 128;             // [2][64] row sumsq
#pragma unroll
        for (int m = 0; m < 2; ++m) {
#pragma unroll
            for (int j = 0; j < 4; ++j) {
                float s = 0.f, q = 0.f;
#pragma unroll
                for (int n = 0; n < 4; ++n) {
                    float v = acc[m][n][j];
                    s += v; q += v * v;
                }
#pragma unroll
                for (int msk = 1; msk < 16; msk <<= 1) {
                    s += __shfl_xor(s, msk);
                    q += __shfl_xor(q, msk);
                }
                if ((lane & 15) == 0) {
                    int rl = wr * 32 + m * 16 + (lane >> 4) * 4 + j;
                    ps[wc * 64 + rl] = s;
                    pq[wc * 64 + rl] = q;
                }
            }
        }
        __syncthreads();
#pragma unroll
        for (int m = 0; m < 2; ++m) {
#pragma unroll
            for (int j = 0; j < 4; ++j) {
                int rl = wr * 32 + m * 16 + (lane >> 4) * 4 + j;
                float S = ps[rl] + ps[64 + rl];
                float Q = pq[rl] + pq[64 + rl];
                float mean = S * (1.f / 128.f);
                float var  = Q * (1.f / 128.f) - mean * mean;
                float rs   = rsqrtf(var + 1e-5f);
                int rg = m0 + rl;
#pragma unroll
                for (int n = 0; n < 4; ++n) {
                    int cg = wc * 64 + n * 16 + (lane & 15);
                    out[(size_t)rg * 128 + cg] =
                        f2bf((acc[m][n][j] - mean) * rs * g[cg] + bb[cg]);
                }
            }
        }
    }
}

// ---------------------------------------------------------------------------
// plain GEMM for the FF (non-gather): C = act(A @ W + bias)  [R6 structure]
// ---------------------------------------------------------------------------
template<int BM, int K, int NTOT, bool RELU>
__global__ __launch_bounds__(256)
void mlp_gemm(const unsigned short* __restrict__ Abase,
              const unsigned short* __restrict__ WT,      // [NTOT][K] bf16
              const float*          __restrict__ bias,    // [NTOT] fp32
              unsigned short*       __restrict__ C)       // [M][NTOT] bf16
{
    constexpr int MI = BM / 32;
    __shared__ unsigned short Alds[BM * 64];
    __shared__ unsigned short Blds[128 * 64];

    const int tid  = threadIdx.x;
    const int lane = tid & 63;
    const int w    = tid >> 6;
    const int wr   = w >> 1, wc = w & 1;
    const int m0   = blockIdx.x * BM;
    const int n0   = blockIdx.y * 128;

    const int lrow = lane >> 3;
    const int soff = ((lane & 7) ^ lrow) * 8;

    const unsigned short *pS[MI], *pB[4];
#pragma unroll
    for (int i = 0; i < MI; ++i)
        pS[i] = Abase + (size_t)(m0 + w * (BM / 4) + i * 8 + lrow) * K + soff;
#pragma unroll
    for (int i = 0; i < 4; ++i)
        pB[i] = WT + (size_t)(n0 + w * 32 + i * 8 + lrow) * K + soff;

    f32x4 acc[MI][4];
#pragma unroll
    for (int m = 0; m < MI; ++m)
#pragma unroll
        for (int n = 0; n < 4; ++n) acc[m][n] = (f32x4){0.f, 0.f, 0.f, 0.f};

#pragma unroll
    for (int k0 = 0; k0 < K; k0 += 64) {
#pragma unroll
        for (int i = 0; i < MI; ++i)
            gl16(pS[i] + k0, Alds + (w * (BM / 4) + i * 8) * 64);
#pragma unroll
        for (int i = 0; i < 4; ++i)
            gl16(pB[i] + k0, Blds + (w * 32 + i * 8) * 64);
        __syncthreads();

#pragma unroll
        for (int ks = 0; ks < 2; ++ks) {
            const int kb = ks * 64 + (lane >> 4) * 16;
            bf16x8 a[MI], b[4];
#pragma unroll
            for (int m = 0; m < MI; ++m) {
                int row = wr * (BM / 2) + m * 16 + (lane & 15);
                a[m] = *reinterpret_cast<const bf16x8*>(
                    (const char*)Alds + row * 128 + (kb ^ ((row & 7) << 4)));
            }
#pragma unroll
            for (int n = 0; n < 4; ++n) {
                int row = wc * 64 + n * 16 + (lane & 15);
                b[n] = *reinterpret_cast<const bf16x8*>(
                    (const char*)Blds + row * 128 + (kb ^ ((row & 7) << 4)));
            }
#pragma unroll
            for (int m = 0; m < MI; ++m)
#pragma unroll
                for (int n = 0; n < 4; ++n)
                    acc[m][n] = __builtin_amdgcn_mfma_f32_16x16x32_bf16(a[m], b[n], acc[m][n], 0, 0, 0);
        }
        __syncthreads();
    }

#pragma unroll
    for (int n = 0; n < 4; ++n) {
        int colg = n0 + wc * 64 + n * 16 + (lane & 15);
        float bi = bias[colg];
#pragma unroll
        for (int m = 0; m < MI; ++m) {
            int rowg = m0 + wr * (BM / 2) + m * 16 + (lane >> 4) * 4;
            unsigned short* cp = C + (size_t)rowg * NTOT + colg;
#pragma unroll
            for (int j = 0; j < 4; ++j) {
                float r = acc[m][n][j] + bi;
                if (RELU) r = fmaxf(r, 0.f);
                cp[(size_t)j * NTOT] = f2bf(r);
            }
        }
    }
}

__global__ __launch_bounds__(256)
void k_deg(const int* __restrict__ ei, int* __restrict__ deg)
{
    int e = blockIdx.x * 256 + threadIdx.x;
    atomicAdd(&deg[ei[E_ + e]], 1);
}

// exclusive scan of deg[32768] -> off[32769]
__global__ __launch_bounds__(1024)
void k_scan(const int* __restrict__ deg, int* __restrict__ off)
{
    __shared__ int part[1024];
    const int t = threadIdx.x;
    const int base = t * 32;
    int loc[32];
    int s = 0;
#pragma unroll
    for (int i = 0; i < 32; ++i) { loc[i] = s; s += deg[base + i]; }
    part[t] = s;
    __syncthreads();
    for (int d = 1; d < 1024; d <<= 1) {
        int v = (t >= d) ? part[t - d] : 0;
        __syncthreads();
        part[t] += v;
        __syncthreads();
    }
    const int pre = (t == 0) ? 0 : part[t - 1];
#pragma unroll
    for (int i = 0; i < 32; ++i) off[base + i] = pre + loc[i];
    if (t == 1023) off[NNODES] = pre + s;
}

__global__ __launch_bounds__(256)
void k_bucket(const int* __restrict__ ei, int* __restrict__ cursor, int* __restrict__ elist)
{
    int e = blockIdx.x * 256 + threadIdx.x;
    int d = ei[E_ + e];
    int pos = atomicAdd(&cursor[d], 1);
    elist[pos] = e;
}

// Fused: agg = mean_{e in CSR[v]} m[e];  out = LN(nodes_in[v] + agg).
__global__ __launch_bounds__(256)
void k_aggln(const unsigned short* __restrict__ m,
             const int* __restrict__ off, const int* __restrict__ elist,
             const unsigned short* __restrict__ nodes_in,
             const float* __restrict__ g, const float* __restrict__ bb,
             unsigned short* __restrict__ nodes_out)
{
    const int v    = blockIdx.x * 4 + (threadIdx.x >> 6);
    const int lane = threadIdx.x & 63;
    const int c    = lane * 2;
    const int beg  = off[v], end = off[v + 1];

    float a0 = 0.f, a1 = 0.f;
    for (int i = beg; i < end; ++i) {
        int e = elist[i];
        unsigned int u = *reinterpret_cast<const unsigned int*>(m + (size_t)e * 128 + c);
        a0 += bf2f((unsigned short)(u & 0xffffu));
        a1 += bf2f((unsigned short)(u >> 16));
    }
    const float inv = 1.f / fmaxf((float)(end - beg), 1.f);
    const size_t o = (size_t)v * 128 + c;
    float x0 = bf2f(nodes_in[o])     + a0 * inv;
    float x1 = bf2f(nodes_in[o + 1]) + a1 * inv;

    float s = x0 + x1, sq = x0 * x0 + x1 * x1;
#pragma unroll
    for (int mm = 1; mm < 64; mm <<= 1) { s += __shfl_xor(s, mm); sq += __shfl_xor(sq, mm); }
    float mean = s * (1.f / 128.f);
    float var  = sq * (1.f / 128.f) - mean * mean;
    float rs   = rsqrtf(var + 1e-5f);
    nodes_out[o]     = f2bf((x0 - mean) * rs * g[c]     + bb[c]);
    nodes_out[o + 1] = f2bf((x1 - mean) * rs * g[c + 1] + bb[c + 1]);
}

// Fused residual + LayerNorm (bf16 residual). F32OUT: fp32 final output.
template<bool F32OUT>
__global__ __launch_bounds__(256)
void k_ln(const unsigned short* __restrict__ base,
          const unsigned short* __restrict__ res,
          const float* __restrict__ g, const float* __restrict__ bb,
          void* __restrict__ outp)
{
    int row  = blockIdx.x * 4 + (threadIdx.x >> 6);
    int lane = threadIdx.x & 63;
    int c    = lane * 2;
    size_t off = (size_t)row * 128 + c;

    float x0 = bf2f(base[off])     + bf2f(res[off]);
    float x1 = bf2f(base[off + 1]) + bf2f(res[off + 1]);
    float s = x0 + x1, sq = x0 * x0 + x1 * x1;
#pragma unroll
    for (int m = 1; m < 64; m <<= 1) { s += __shfl_xor(s, m); sq += __shfl_xor(sq, m); }
    float mean = s * (1.f / 128.f);
    float var  = sq * (1.f / 128.f) - mean * mean;
    float rs   = rsqrtf(var + 1e-5f);
    float y0 = (x0 - mean) * rs * g[c]     + bb[c];
    float y1 = (x1 - mean) * rs * g[c + 1] + bb[c + 1];
    if (F32OUT) {
        ((float*)outp)[off]     = y0;
        ((float*)outp)[off + 1] = y1;
    } else {
        ((unsigned short*)outp)[off]     = f2bf(y0);
        ((unsigned short*)outp)[off + 1] = f2bf(y1);
    }
}

// ---------------------------------------------------------------------------
extern "C" void kernel_launch(void* const* d_in, const int* in_sizes, int n_in,
                              void* d_out, int out_size, void* d_ws, size_t ws_size,
                              hipStream_t stream)
{
    const float* x      = (const float*)d_in[0];
    const int*   ei     = (const int*)d_in[1];
    const float* eat0   = (const float*)d_in[2];
    const float* msg_W0 = (const float*)d_in[3];
    const float* msg_b0 = (const float*)d_in[4];
    const float* msg_W1 = (const float*)d_in[5];
    const float* msg_b1 = (const float*)d_in[6];
    const float* msg_W2 = (const float*)d_in[7];
    const float* msg_b2 = (const float*)d_in[8];
    const float* n0g    = (const float*)d_in[9];
    const float* n0b    = (const float*)d_in[10];
    const float* ff_W0  = (const float*)d_in[11];
    const float* ff_b0  = (const float*)d_in[12];
    const float* ff_W1  = (const float*)d_in[13];
    const float* ff_b1  = (const float*)d_in[14];
    const float* n1g    = (const float*)d_in[15];
    const float* n1b    = (const float*)d_in[16];
    const float* e_W0   = (const float*)d_in[17];
    const float* e_b0   = (const float*)d_in[18];
    const float* e_W1   = (const float*)d_in[19];
    const float* e_b1   = (const float*)d_in[20];
    const float* e_W2   = (const float*)d_in[21];
    const float* e_b2   = (const float*)d_in[22];
    const float* eng    = (const float*)d_in[23];
    const float* enb    = (const float*)d_in[24];

    char* ws = (char*)d_ws;
    const size_t MB = (size_t)1 << 20;
    unsigned short* nodes = (unsigned short*)(ws);                 // 8 MB bf16
    unsigned short* edgec = (unsigned short*)(ws + 8 * MB);        // 64 MB bf16
    unsigned short* tmpA  = (unsigned short*)(ws + 72 * MB);       // 64 MB (msg out m)
    unsigned short* ffh   = (unsigned short*)(ws + 136 * MB);      // 32 MB (FF hidden)
    unsigned short* ffo   = tmpA;                                  // alias (phase-disjoint)
    unsigned short* wt    = (unsigned short*)(ws + 200 * MB);      // ~1 MB bf16
    int*            deg   = (int*)(ws + 202 * MB);                 // 128 KB
    int*            off   = (int*)(ws + 202 * MB + 256 * 1024);    // 128 KB + 4
    int*            cur   = (int*)(ws + 202 * MB + 512 * 1024);    // 128 KB
    int*            elist = (int*)(ws + 202 * MB + 768 * 1024);    // 1 MB

    // weight transpose targets (bf16 [N][K])
    unsigned short* p = wt;
    unsigned short *wt_m0[L_], *wt_m1[L_], *wt_m2[L_], *wt_f0[L_], *wt_f1[L_];
    for (int l = 0; l < L_; ++l) {
        wt_m0[l] = p; p += 384 * 128;
        wt_m1[l] = p; p += 128 * 128;
        wt_m2[l] = p; p += 128 * 128;
        wt_f0[l] = p; p += 128 * 512;
        wt_f1[l] = p; p += 512 * 128;
    }
    unsigned short* wt_e0 = p; p += 384 * 128;
    unsigned short* wt_e1 = p; p += 128 * 128;
    unsigned short* wt_e2 = p; p += 128 * 128;

    TDA tda; int toff = 0, ti = 0;
    auto addT = [&](const float* s, unsigned short* d, int K, int N) {
        tda.v[ti++] = TD{s, d, toff, K, (N == 512 ? 9 : 7)};
        toff += K * N;
    };
    for (int l = 0; l < L_; ++l) {
        addT(msg_W0 + l * 384 * 128, wt_m0[l], 384, 128);
        addT(msg_W1 + l * 128 * 128, wt_m1[l], 128, 128);
        addT(msg_W2 + l * 128 * 128, wt_m2[l], 128, 128);
        addT(ff_W0  + l * 128 * 512, wt_f0[l], 128, 512);
        addT(ff_W1  + l * 512 * 128, wt_f1[l], 512, 128);
    }
    addT(e_W0, wt_e0, 384, 128);   // layer-0 edge update only (layer-1's is dead code)
    addT(e_W1, wt_e1, 128, 128);
    addT(e_W2, wt_e2, 128, 128);
    tda.total = toff;
    k_transpose_all<<<(toff + 255) / 256, 256, 0, stream>>>(tda);

    const int n4a = NNODES * 128 / 4, n4b = E_ * 128 / 4;
    k_cvt2<<<(n4a + n4b + 255) / 256, 256, 0, stream>>>(x, nodes, n4a, eat0, edgec, n4b);

    // CSR build (once — edge_index constant across layers)
    hipMemsetAsync(deg, 0, NNODES * sizeof(int), stream);
    k_deg<<<E_ / 256, 256, 0, stream>>>(ei, deg);
    k_scan<<<1, 1024, 0, stream>>>(deg, off);
    hipMemcpyAsync(cur, off, NNODES * sizeof(int), hipMemcpyDeviceToDevice, stream);
    k_bucket<<<E_ / 256, 256, 0, stream>>>(ei, cur, elist);

    const dim3 gE(E_ / 64, 1), gN64(NNODES / 64, 1), gF0(NNODES / 128, 4);

    for (int l = 0; l < L_; ++l) {
        // --- fused message MLP (3 GEMMs in one kernel, counted-vmcnt pipeline) ---
        fused_mlp3<false><<<gE, 256, 0, stream>>>(nodes, edgec, ei,
            wt_m0[l], wt_m1[l], wt_m2[l],
            msg_b0 + l * 128, msg_b1 + l * 128, msg_b2 + l * 128,
            nullptr, nullptr, tmpA);
        k_aggln<<<NNODES / 4, 256, 0, stream>>>(tmpA, off, elist, nodes,
            n0g + l * 128, n0b + l * 128, nodes);
        // --- feedforward + LN ---
        mlp_gemm<128, 128, 512, true ><<<gF0, 256, 0, stream>>>(nodes, wt_f0[l], ff_b0 + l * 512, ffh);
        mlp_gemm<64,  512, 128, false><<<gN64, 256, 0, stream>>>(ffh, wt_f1[l], ff_b1 + l * 128, ffo);
        if (l == L_ - 1) {
            k_ln<true ><<<NNODES / 4, 256, 0, stream>>>(nodes, ffo, n1g + l * 128, n1b + l * 128, d_out);
        } else {
            k_ln<false><<<NNODES / 4, 256, 0, stream>>>(nodes, ffo, n1g + l * 128, n1b + l * 128, nodes);
        }
        // --- fused edge update incl. residual+LN (only layer 0; layer-1's is dead) ---
        if (l == 0) {
            fused_mlp3<true><<<gE, 256, 0, stream>>>(nodes, edgec, ei,
                wt_e0, wt_e1, wt_e2, e_b0, e_b1, e_b2, eng, enb, edgec);
        }
    }
}

// Round 11
// 477.044 us; speedup vs baseline: 1.8412x; 1.0097x over previous
//
#include <hip/hip_runtime.h>

#define E_      262144
#define NNODES  32768
#define L_      2

typedef __attribute__((ext_vector_type(8))) short  bf16x8;
typedef __attribute__((ext_vector_type(4))) float  f32x4;

typedef __attribute__((address_space(1))) const unsigned int gu32;
typedef __attribute__((address_space(3))) unsigned int       lu32;

__device__ __forceinline__ void gl16(const void* g, void* l) {
    // async global->LDS, 16B/lane; LDS dest = wave-uniform base + lane*16
    __builtin_amdgcn_global_load_lds((gu32*)g, (lu32*)l, 16, 0, 0);
}

__device__ __forceinline__ float bf2f(unsigned short u) {
    union { unsigned int i; float f; } v; v.i = ((unsigned int)u) << 16; return v.f;
}
__device__ __forceinline__ unsigned short f2bf(float f) {
    union { float f; unsigned int i; } v; v.f = f;
    unsigned int r = v.i + 0x7FFFu + ((v.i >> 16) & 1u);   // round-nearest-even
    return (unsigned short)(r >> 16);
}

// combined fp32->bf16 for nodes + edge_attr
__global__ __launch_bounds__(256)
void k_cvt2(const float* __restrict__ a, unsigned short* __restrict__ oa, int n4a,
            const float* __restrict__ b, unsigned short* __restrict__ ob, int n4b)
{
    int i = blockIdx.x * 256 + threadIdx.x;
    if (i < n4a) {
        float4 v = reinterpret_cast<const float4*>(a)[i];
        ushort4 o; o.x = f2bf(v.x); o.y = f2bf(v.y); o.z = f2bf(v.z); o.w = f2bf(v.w);
        reinterpret_cast<ushort4*>(oa)[i] = o;
    } else if (i < n4a + n4b) {
        int j = i - n4a;
        float4 v = reinterpret_cast<const float4*>(b)[j];
        ushort4 o; o.x = f2bf(v.x); o.y = f2bf(v.y); o.z = f2bf(v.z); o.w = f2bf(v.w);
        reinterpret_cast<ushort4*>(ob)[j] = o;
    }
}

// batched weight transpose: 19 blocks in one dispatch. [K][N] fp32 -> [N][K] bf16
struct TD  { const float* s; unsigned short* d; int off; int K; int nsh; };
struct TDA { TD v[19]; int total; };

__global__ __launch_bounds__(256)
void k_transpose_all(TDA t)
{
    int idx = blockIdx.x * 256 + threadIdx.x;
    if (idx >= t.total) return;
    int j = 0;
#pragma unroll
    for (int m = 1; m < 19; ++m) if (idx >= t.v[m].off) j = m;
    const TD& td = t.v[j];
    int local = idx - td.off;
    int k = local >> td.nsh;
    int n = local & ((1 << td.nsh) - 1);
    td.d[(size_t)n * td.K + k] = f2bf(td.s[local]);
}

// ---------------------------------------------------------------------------
// PQ pre-pass GEMM:  PQ[v] = bf16[ nodes[v]@W0a + b0 | nodes[v]@W0c ]
// WT = [a^T ; c^T] as [256][128] bf16. BM=64 tile, grid (NNODES/64, 2).
// ---------------------------------------------------------------------------
__global__ __launch_bounds__(256)
void pq_gemm(const unsigned short* __restrict__ A,      // [NNODES][128] bf16
             const unsigned short* __restrict__ WT,     // [256][128] bf16
             const float* __restrict__ b0,              // [128] fp32
             unsigned short* __restrict__ PQ)           // [NNODES][256] bf16
{
    __shared__ unsigned short Alds[64 * 64];
    __shared__ unsigned short Blds[128 * 64];

    const int tid  = threadIdx.x;
    const int lane = tid & 63;
    const int w    = tid >> 6;
    const int wr   = w >> 1, wc = w & 1;
    const int m0   = blockIdx.x * 64;
    const int n0   = blockIdx.y * 128;

    const int lrow = lane >> 3;
    const int soff = ((lane & 7) ^ lrow) * 8;

    char* Ac = (char*)Alds; char* Bc = (char*)Blds;

    const unsigned short *pS[2], *pB[4];
#pragma unroll
    for (int i = 0; i < 2; ++i)
        pS[i] = A + (size_t)(m0 + w * 16 + i * 8 + lrow) * 128 + soff;
#pragma unroll
    for (int i = 0; i < 4; ++i)
        pB[i] = WT + (size_t)(n0 + w * 32 + i * 8 + lrow) * 128 + soff;

    f32x4 acc[2][4];
#pragma unroll
    for (int m = 0; m < 2; ++m)
#pragma unroll
        for (int n = 0; n < 4; ++n) acc[m][n] = (f32x4){0.f, 0.f, 0.f, 0.f};

#pragma unroll
    for (int k0 = 0; k0 < 128; k0 += 64) {
#pragma unroll
        for (int i = 0; i < 2; ++i) gl16(pS[i] + k0, Ac + (w * 16 + i * 8) * 128);
#pragma unroll
        for (int i = 0; i < 4; ++i) gl16(pB[i] + k0, Bc + (w * 32 + i * 8) * 128);
        __syncthreads();
#pragma unroll
        for (int ks = 0; ks < 2; ++ks) {
            const int kb = ks * 64 + (lane >> 4) * 16;
            bf16x8 a[2], b[4];
#pragma unroll
            for (int m = 0; m < 2; ++m) {
                int row = wr * 32 + m * 16 + (lane & 15);
                a[m] = *reinterpret_cast<const bf16x8*>(Ac + row * 128 + (kb ^ ((row & 7) << 4)));
            }
#pragma unroll
            for (int n = 0; n < 4; ++n) {
                int row = wc * 64 + n * 16 + (lane & 15);
                b[n] = *reinterpret_cast<const bf16x8*>(Bc + row * 128 + (kb ^ ((row & 7) << 4)));
            }
#pragma unroll
            for (int m = 0; m < 2; ++m)
#pragma unroll
                for (int n = 0; n < 4; ++n)
                    acc[m][n] = __builtin_amdgcn_mfma_f32_16x16x32_bf16(a[m], b[n], acc[m][n], 0, 0, 0);
        }
        __syncthreads();
    }

#pragma unroll
    for (int n = 0; n < 4; ++n) {
        int colg = n0 + wc * 64 + n * 16 + (lane & 15);
        float bi = (colg < 128) ? b0[colg] : 0.f;
#pragma unroll
        for (int m = 0; m < 2; ++m) {
            int rowg = m0 + wr * 32 + m * 16 + (lane >> 4) * 4;
            unsigned short* cp = PQ + (size_t)rowg * 256 + colg;
#pragma unroll
            for (int j = 0; j < 4; ++j)
                cp[(size_t)j * 256] = f2bf(acc[m][n][j] + bi);
        }
    }
}

// ---------------------------------------------------------------------------
// FUSED 3-stage edge MLP (factorized, bf16 PQ), BM=64, R6-proven barriers:
//   Hraw = eattr @ W0b                               (K=128, 2 steps)
//   h1   = relu(Hraw + P[src] + Q[dst])              (PQ bf16; b0 folded in P)
//   h2   = relu(h1 @ W1 + b1);  m = h2 @ W2 + b2     (2+2 steps)
//   LNEPI=0: out[e]=m;  LNEPI=1: out[e]=LN(ein[e]+m)*g+b
// LDS: S0 8KB + SB 16KB + H 16KB = 40KB -> 4 blocks/CU (launch_bounds(256,4)).
// ---------------------------------------------------------------------------
template<bool LNEPI>
__global__ __launch_bounds__(256, 4)
void fused_mlp3(const unsigned short* __restrict__ ein,     // [E][128] A input (+residual)
                const unsigned short* __restrict__ PQb,     // [NNODES][256] bf16
                const int*            __restrict__ ei,      // [2][E]
                const unsigned short* __restrict__ W0bT,    // [128][128]
                const unsigned short* __restrict__ W1T,     // [128][128]
                const unsigned short* __restrict__ W2T,     // [128][128]
                const float* __restrict__ b1, const float* __restrict__ b2,
                const float* __restrict__ g,  const float* __restrict__ bb,
                unsigned short* __restrict__ out)           // [E][128]
{
    __shared__ unsigned short S0[64 * 64];     //  8KB A-stage
    __shared__ unsigned short SB[128 * 64];    // 16KB W-stage / LN scratch
    __shared__ unsigned short H [64 * 128];    // 16KB h1/h2

    const int tid  = threadIdx.x;
    const int lane = tid & 63;
    const int w    = tid >> 6;
    const int wr   = w >> 1, wc = w & 1;
    const int m0   = blockIdx.x * 64;

    const int lrow = lane >> 3;
    const int soff = ((lane & 7) ^ lrow) * 8;

    char* S0c = (char*)S0; char* SBc = (char*)SB; char* Hc = (char*)H;

    const unsigned short* pA[2];
#pragma unroll
    for (int i = 0; i < 2; ++i)
        pA[i] = ein + (size_t)(m0 + w * 16 + i * 8 + lrow) * 128 + soff;

    f32x4 acc[2][4];
    auto zacc = [&]() {
#pragma unroll
        for (int m = 0; m < 2; ++m)
#pragma unroll
            for (int n = 0; n < 4; ++n) acc[m][n] = (f32x4){0.f, 0.f, 0.f, 0.f};
    };

    auto stageA = [&](int k0) {
#pragma unroll
        for (int i = 0; i < 2; ++i)
            gl16(pA[i] + k0, S0c + (w * 16 + i * 8) * 128);
    };
    auto stageW = [&](const unsigned short* WT, int k0) {
#pragma unroll
        for (int i = 0; i < 4; ++i)
            gl16(WT + (size_t)(w * 32 + i * 8 + lrow) * 128 + k0 + soff,
                 SBc + (w * 32 + i * 8) * 128);
    };

    // MFMA step over 64 K-elems: A at (base, row stride abytes, byte offset kb0)
    auto mma = [&](const char* Ab, int abytes, int kb0) {
#pragma unroll
        for (int ks = 0; ks < 2; ++ks) {
            const int kb = ks * 64 + (lane >> 4) * 16;
            bf16x8 a[2], b[4];
#pragma unroll
            for (int m = 0; m < 2; ++m) {
                int row = wr * 32 + m * 16 + (lane & 15);
                a[m] = *reinterpret_cast<const bf16x8*>(
                    Ab + row * abytes + ((kb0 + kb) ^ ((row & 7) << 4)));
            }
#pragma unroll
            for (int n = 0; n < 4; ++n) {
                int row = wc * 64 + n * 16 + (lane & 15);
                b[n] = *reinterpret_cast<const bf16x8*>(
                    SBc + row * 128 + (kb ^ ((row & 7) << 4)));
            }
#pragma unroll
            for (int m = 0; m < 2; ++m)
#pragma unroll
                for (int n = 0; n < 4; ++n)
                    acc[m][n] = __builtin_amdgcn_mfma_f32_16x16x32_bf16(a[m], b[n], acc[m][n], 0, 0, 0);
        }
    };

    // write acc -> H [64 rows][256B], swizzled; optional bias/relu
    auto towrite = [&](const float* bias, bool relu) {
#pragma unroll
        for (int n = 0; n < 4; ++n) {
            int cg = wc * 64 + n * 16 + (lane & 15);
            float bi = bias ? bias[cg] : 0.f;
#pragma unroll
            for (int m = 0; m < 2; ++m) {
#pragma unroll
                for (int j = 0; j < 4; ++j) {
                    int rg = wr * 32 + m * 16 + (lane >> 4) * 4 + j;
                    float v = acc[m][n][j] + bi;
                    if (relu) v = fmaxf(v, 0.f);
                    *(unsigned short*)(Hc + rg * 256 + ((2 * cg) ^ ((rg & 7) << 4))) = f2bf(v);
                }
            }
        }
    };

    // h1 = relu(Hraw + P[src] + Q[dst]) : thread -> (row r, 32-col strip), bf16 PQ
    auto pq_pass = [&]() {
        const int r  = tid >> 2;
        const int c0 = (tid & 3) * 32;
        const int sv = ei[m0 + r], dv = ei[E_ + m0 + r];
        const unsigned short* Pp = PQb + (size_t)sv * 256 + c0;
        const unsigned short* Qp = PQb + (size_t)dv * 256 + 128 + c0;
#pragma unroll
        for (int i = 0; i < 4; ++i) {
            char* hp = Hc + r * 256 + (((c0 + i * 8) * 2) ^ ((r & 7) << 4));
            bf16x8 hv = *reinterpret_cast<bf16x8*>(hp);
            bf16x8 pv = *reinterpret_cast<const bf16x8*>(Pp + i * 8);
            bf16x8 qv = *reinterpret_cast<const bf16x8*>(Qp + i * 8);
            bf16x8 o;
#pragma unroll
            for (int jj = 0; jj < 8; ++jj)
                o[jj] = (short)f2bf(fmaxf(
                    bf2f((unsigned short)hv[jj]) + bf2f((unsigned short)pv[jj])
                    + bf2f((unsigned short)qv[jj]), 0.f));
            *reinterpret_cast<bf16x8*>(hp) = o;
        }
    };

    // ======== phase 1: Hraw = eattr @ W0b (K=128, 2 steps) ========
    zacc();
#pragma unroll
    for (int t = 0; t < 2; ++t) {
        stageA(t * 64); stageW(W0bT, t * 64);
        __syncthreads();
        mma(S0c, 128, 0);
        __syncthreads();
    }
    towrite(nullptr, false);
    __syncthreads();           // Hraw visible to all
    pq_pass();                 // h1 in H
    // ======== phase 2: h2 = relu(h1 @ W1 + b1) ========
    zacc();
#pragma unroll
    for (int t = 0; t < 2; ++t) {
        stageW(W1T, t * 64);
        __syncthreads();       // t=0: also makes pq_pass writes visible
        mma(Hc, 256, t * 128);
        __syncthreads();
    }
    towrite(b1, true);         // h2 over h1 (all reads done at loop-final barrier)
    // ======== phase 3: m = h2 @ W2 + b2 ========
    zacc();
#pragma unroll
    for (int t = 0; t < 2; ++t) {
        stageW(W2T, t * 64);
        __syncthreads();       // t=0: h2 visible
        mma(Hc, 256, t * 128);
        __syncthreads();
    }

    // ======== epilogue ========
    if (!LNEPI) {
#pragma unroll
        for (int n = 0; n < 4; ++n) {
            int cg = wc * 64 + n * 16 + (lane & 15);
            float bi = b2[cg];
#pragma unroll
            for (int m = 0; m < 2; ++m) {
                int rg = m0 + wr * 32 + m * 16 + (lane >> 4) * 4;
                unsigned short* cp = out + (size_t)rg * 128 + cg;
#pragma unroll
                for (int j = 0; j < 4; ++j)
                    cp[(size_t)j * 128] = f2bf(acc[m][n][j] + bi);
            }
        }
    } else {
        // residual + LayerNorm fused. vals = m + b2 + ein.
#pragma unroll
        for (int n = 0; n < 4; ++n) {
            int cg = wc * 64 + n * 16 + (lane & 15);
            float bi = b2[cg];
#pragma unroll
            for (int m = 0; m < 2; ++m) {
#pragma unroll
                for (int j = 0; j < 4; ++j) {
                    int rg = m0 + wr * 32 + m * 16 + (lane >> 4) * 4 + j;
                    acc[m][n][j] += bi + bf2f(ein[(size_t)rg * 128 + cg]);
                }
            }
        }
        float* ps = (float*)SBc;          // [2][64] row sums   (SB dead)
        float* pq = ps + 128;             // [2][64] row sumsq
#pragma unroll
        for (int m = 0; m < 2; ++m) {
#pragma unroll
            for (int j = 0; j < 4; ++j) {
                float s = 0.f, q = 0.f;
#pragma unroll
                for (int n = 0; n < 4; ++n) {
                    float v = acc[m][n][j];
                    s += v; q += v * v;
                }
#pragma unroll
                for (int msk = 1; msk < 16; msk <<= 1) {
                    s += __shfl_xor(s, msk);
                    q += __shfl_xor(q, msk);
                }
                if ((lane & 15) == 0) {
                    int rl = wr * 32 + m * 16 + (lane >> 4) * 4 + j;
                    ps[wc * 64 + rl] = s;
                    pq[wc * 64 + rl] = q;
                }
            }
        }
        __syncthreads();
#pragma unroll
        for (int m = 0; m < 2; ++m) {
#pragma unroll
            for (int j = 0; j < 4; ++j) {
                int rl = wr * 32 + m * 16 + (lane >> 4) * 4 + j;
                float S = ps[rl] + ps[64 + rl];
                float Q = pq[rl] + pq[64 + rl];
                float mean = S * (1.f / 128.f);
                float var  = Q * (1.f / 128.f) - mean * mean;
                float rs   = rsqrtf(var + 1e-5f);
                int rg = m0 + rl;
#pragma unroll
                for (int n = 0; n < 4; ++n) {
                    int cg = wc * 64 + n * 16 + (lane & 15);
                    out[(size_t)rg * 128 + cg] =
                        f2bf((acc[m][n][j] - mean) * rs * g[cg] + bb[cg]);
                }
            }
        }
    }
}

// ---------------------------------------------------------------------------
// plain GEMM for the FF (non-gather): C = act(A @ W + bias)  [R6 structure]
// ---------------------------------------------------------------------------
template<int BM, int K, int NTOT, bool RELU>
__global__ __launch_bounds__(256)
void mlp_gemm(const unsigned short* __restrict__ Abase,
              const unsigned short* __restrict__ WT,      // [NTOT][K] bf16
              const float*          __restrict__ bias,    // [NTOT] fp32
              unsigned short*       __restrict__ C)       // [M][NTOT] bf16
{
    constexpr int MI = BM / 32;
    __shared__ unsigned short Alds[BM * 64];
    __shared__ unsigned short Blds[128 * 64];

    const int tid  = threadIdx.x;
    const int lane = tid & 63;
    const int w    = tid >> 6;
    const int wr   = w >> 1, wc = w & 1;
    const int m0   = blockIdx.x * BM;
    const int n0   = blockIdx.y * 128;

    const int lrow = lane >> 3;
    const int soff = ((lane & 7) ^ lrow) * 8;

    const unsigned short *pS[MI], *pB[4];
#pragma unroll
    for (int i = 0; i < MI; ++i)
        pS[i] = Abase + (size_t)(m0 + w * (BM / 4) + i * 8 + lrow) * K + soff;
#pragma unroll
    for (int i = 0; i < 4; ++i)
        pB[i] = WT + (size_t)(n0 + w * 32 + i * 8 + lrow) * K + soff;

    f32x4 acc[MI][4];
#pragma unroll
    for (int m = 0; m < MI; ++m)
#pragma unroll
        for (int n = 0; n < 4; ++n) acc[m][n] = (f32x4){0.f, 0.f, 0.f, 0.f};

#pragma unroll
    for (int k0 = 0; k0 < K; k0 += 64) {
#pragma unroll
        for (int i = 0; i < MI; ++i)
            gl16(pS[i] + k0, Alds + (w * (BM / 4) + i * 8) * 64);
#pragma unroll
        for (int i = 0; i < 4; ++i)
            gl16(pB[i] + k0, Blds + (w * 32 + i * 8) * 64);
        __syncthreads();

#pragma unroll
        for (int ks = 0; ks < 2; ++ks) {
            const int kb = ks * 64 + (lane >> 4) * 16;
            bf16x8 a[MI], b[4];
#pragma unroll
            for (int m = 0; m < MI; ++m) {
                int row = wr * (BM / 2) + m * 16 + (lane & 15);
                a[m] = *reinterpret_cast<const bf16x8*>(
                    (const char*)Alds + row * 128 + (kb ^ ((row & 7) << 4)));
            }
#pragma unroll
            for (int n = 0; n < 4; ++n) {
                int row = wc * 64 + n * 16 + (lane & 15);
                b[n] = *reinterpret_cast<const bf16x8*>(
                    (const char*)Blds + row * 128 + (kb ^ ((row & 7) << 4)));
            }
#pragma unroll
            for (int m = 0; m < MI; ++m)
#pragma unroll
                for (int n = 0; n < 4; ++n)
                    acc[m][n] = __builtin_amdgcn_mfma_f32_16x16x32_bf16(a[m], b[n], acc[m][n], 0, 0, 0);
        }
        __syncthreads();
    }

#pragma unroll
    for (int n = 0; n < 4; ++n) {
        int colg = n0 + wc * 64 + n * 16 + (lane & 15);
        float bi = bias[colg];
#pragma unroll
        for (int m = 0; m < MI; ++m) {
            int rowg = m0 + wr * (BM / 2) + m * 16 + (lane >> 4) * 4;
            unsigned short* cp = C + (size_t)rowg * NTOT + colg;
#pragma unroll
            for (int j = 0; j < 4; ++j) {
                float r = acc[m][n][j] + bi;
                if (RELU) r = fmaxf(r, 0.f);
                cp[(size_t)j * NTOT] = f2bf(r);
            }
        }
    }
}

__global__ __launch_bounds__(256)
void k_deg(const int* __restrict__ ei, int* __restrict__ deg)
{
    int e = blockIdx.x * 256 + threadIdx.x;
    atomicAdd(&deg[ei[E_ + e]], 1);
}

// exclusive scan of deg[32768] -> off[32769]
__global__ __launch_bounds__(1024)
void k_scan(const int* __restrict__ deg, int* __restrict__ off)
{
    __shared__ int part[1024];
    const int t = threadIdx.x;
    const int base = t * 32;
    int loc[32];
    int s = 0;
#pragma unroll
    for (int i = 0; i < 32; ++i) { loc[i] = s; s += deg[base + i]; }
    part[t] = s;
    __syncthreads();
    for (int d = 1; d < 1024; d <<= 1) {
        int v = (t >= d) ? part[t - d] : 0;
        __syncthreads();
        part[t] += v;
        __syncthreads();
    }
    const int pre = (t == 0) ? 0 : part[t - 1];
#pragma unroll
    for (int i = 0; i < 32; ++i) off[base + i] = pre + loc[i];
    if (t == 1023) off[NNODES] = pre + s;
}

__global__ __launch_bounds__(256)
void k_bucket(const int* __restrict__ ei, int* __restrict__ cursor, int* __restrict__ elist)
{
    int e = blockIdx.x * 256 + threadIdx.x;
    int d = ei[E_ + e];
    int pos = atomicAdd(&cursor[d], 1);
    elist[pos] = e;
}

// Fused: agg = mean_{e in CSR[v]} m[e];  out = LN(nodes_in[v] + agg).
__global__ __launch_bounds__(256)
void k_aggln(const unsigned short* __restrict__ m,
             const int* __restrict__ off, const int* __restrict__ elist,
             const unsigned short* __restrict__ nodes_in,
             const float* __restrict__ g, const float* __restrict__ bb,
             unsigned short* __restrict__ nodes_out)
{
    const int v    = blockIdx.x * 4 + (threadIdx.x >> 6);
    const int lane = threadIdx.x & 63;
    const int c    = lane * 2;
    const int beg  = off[v], end = off[v + 1];

    float a0 = 0.f, a1 = 0.f;
    for (int i = beg; i < end; ++i) {
        int e = elist[i];
        unsigned int u = *reinterpret_cast<const unsigned int*>(m + (size_t)e * 128 + c);
        a0 += bf2f((unsigned short)(u & 0xffffu));
        a1 += bf2f((unsigned short)(u >> 16));
    }
    const float inv = 1.f / fmaxf((float)(end - beg), 1.f);
    const size_t o = (size_t)v * 128 + c;
    float x0 = bf2f(nodes_in[o])     + a0 * inv;
    float x1 = bf2f(nodes_in[o + 1]) + a1 * inv;

    float s = x0 + x1, sq = x0 * x0 + x1 * x1;
#pragma unroll
    for (int mm = 1; mm < 64; mm <<= 1) { s += __shfl_xor(s, mm); sq += __shfl_xor(sq, mm); }
    float mean = s * (1.f / 128.f);
    float var  = sq * (1.f / 128.f) - mean * mean;
    float rs   = rsqrtf(var + 1e-5f);
    nodes_out[o]     = f2bf((x0 - mean) * rs * g[c]     + bb[c]);
    nodes_out[o + 1] = f2bf((x1 - mean) * rs * g[c + 1] + bb[c + 1]);
}

// Fused residual + LayerNorm (bf16 residual). F32OUT: fp32 final output.
template<bool F32OUT>
__global__ __launch_bounds__(256)
void k_ln(const unsigned short* __restrict__ base,
          const unsigned short* __restrict__ res,
          const float* __restrict__ g, const float* __restrict__ bb,
          void* __restrict__ outp)
{
    int row  = blockIdx.x * 4 + (threadIdx.x >> 6);
    int lane = threadIdx.x & 63;
    int c    = lane * 2;
    size_t off = (size_t)row * 128 + c;

    float x0 = bf2f(base[off])     + bf2f(res[off]);
    float x1 = bf2f(base[off + 1]) + bf2f(res[off + 1]);
    float s = x0 + x1, sq = x0 * x0 + x1 * x1;
#pragma unroll
    for (int m = 1; m < 64; m <<= 1) { s += __shfl_xor(s, m); sq += __shfl_xor(sq, m); }
    float mean = s * (1.f / 128.f);
    float var  = sq * (1.f / 128.f) - mean * mean;
    float rs   = rsqrtf(var + 1e-5f);
    float y0 = (x0 - mean) * rs * g[c]     + bb[c];
    float y1 = (x1 - mean) * rs * g[c + 1] + bb[c + 1];
    if (F32OUT) {
        ((float*)outp)[off]     = y0;
        ((float*)outp)[off + 1] = y1;
    } else {
        ((unsigned short*)outp)[off]     = f2bf(y0);
        ((unsigned short*)outp)[off + 1] = f2bf(y1);
    }
}

// ---------------------------------------------------------------------------
extern "C" void kernel_launch(void* const* d_in, const int* in_sizes, int n_in,
                              void* d_out, int out_size, void* d_ws, size_t ws_size,
                              hipStream_t stream)
{
    const float* x      = (const float*)d_in[0];
    const int*   ei     = (const int*)d_in[1];
    const float* eat0   = (const float*)d_in[2];
    const float* msg_W0 = (const float*)d_in[3];
    const float* msg_b0 = (const float*)d_in[4];
    const float* msg_W1 = (const float*)d_in[5];
    const float* msg_b1 = (const float*)d_in[6];
    const float* msg_W2 = (const float*)d_in[7];
    const float* msg_b2 = (const float*)d_in[8];
    const float* n0g    = (const float*)d_in[9];
    const float* n0b    = (const float*)d_in[10];
    const float* ff_W0  = (const float*)d_in[11];
    const float* ff_b0  = (const float*)d_in[12];
    const float* ff_W1  = (const float*)d_in[13];
    const float* ff_b1  = (const float*)d_in[14];
    const float* n1g    = (const float*)d_in[15];
    const float* n1b    = (const float*)d_in[16];
    const float* e_W0   = (const float*)d_in[17];
    const float* e_b0   = (const float*)d_in[18];
    const float* e_W1   = (const float*)d_in[19];
    const float* e_b1   = (const float*)d_in[20];
    const float* e_W2   = (const float*)d_in[21];
    const float* e_b2   = (const float*)d_in[22];
    const float* eng    = (const float*)d_in[23];
    const float* enb    = (const float*)d_in[24];

    char* ws = (char*)d_ws;
    const size_t MB = (size_t)1 << 20;
    unsigned short* nodes = (unsigned short*)(ws);                 // 8 MB bf16
    unsigned short* edgec = (unsigned short*)(ws + 8 * MB);        // 64 MB bf16
    unsigned short* tmpA  = (unsigned short*)(ws + 72 * MB);       // 64 MB (msg out m)
    unsigned short* ffh   = (unsigned short*)(ws + 136 * MB);      // 32 MB (FF hidden)
    unsigned short* PQb   = (unsigned short*)(ws + 168 * MB);      // 16 MB bf16 [N][256]
    unsigned short* ffo   = tmpA;                                  // alias (phase-disjoint)
    unsigned short* wt    = (unsigned short*)(ws + 200 * MB);      // ~1 MB bf16
    int*            deg   = (int*)(ws + 202 * MB);                 // 128 KB
    int*            off   = (int*)(ws + 202 * MB + 256 * 1024);    // 128 KB + 4
    int*            cur   = (int*)(ws + 202 * MB + 512 * 1024);    // 128 KB
    int*            elist = (int*)(ws + 202 * MB + 768 * 1024);    // 1 MB

    // weight transpose targets (bf16 [N][K]); W0 split into a(src)/b(eattr)/c(dst)
    unsigned short* p = wt;
    unsigned short *wt_mac[L_], *wt_mb[L_], *wt_m1[L_], *wt_m2[L_], *wt_f0[L_], *wt_f1[L_];
    for (int l = 0; l < L_; ++l) {
        wt_mac[l] = p; p += 256 * 128;        // [a^T ; c^T]
        wt_mb[l]  = p; p += 128 * 128;
        wt_m1[l]  = p; p += 128 * 128;
        wt_m2[l]  = p; p += 128 * 128;
        wt_f0[l]  = p; p += 128 * 512;
        wt_f1[l]  = p; p += 512 * 128;
    }
    unsigned short* wt_eac = p; p += 256 * 128;
    unsigned short* wt_eb  = p; p += 128 * 128;
    unsigned short* wt_e1  = p; p += 128 * 128;
    unsigned short* wt_e2  = p; p += 128 * 128;

    TDA tda; int toff = 0, ti = 0;
    auto addT = [&](const float* s, unsigned short* d, int K, int N) {
        tda.v[ti++] = TD{s, d, toff, K, (N == 512 ? 9 : 7)};
        toff += K * N;
    };
    for (int l = 0; l < L_; ++l) {
        const float* W0 = msg_W0 + l * 384 * 128;
        addT(W0,             wt_mac[l],         128, 128);   // a: rows 0..127
        addT(W0 + 256 * 128, wt_mac[l] + 16384, 128, 128);   // c: rows 256..383
        addT(W0 + 128 * 128, wt_mb[l],          128, 128);   // b: rows 128..255
        addT(msg_W1 + l * 128 * 128, wt_m1[l], 128, 128);
        addT(msg_W2 + l * 128 * 128, wt_m2[l], 128, 128);
        addT(ff_W0  + l * 128 * 512, wt_f0[l], 128, 512);
        addT(ff_W1  + l * 512 * 128, wt_f1[l], 512, 128);
    }
    addT(e_W0,             wt_eac,         128, 128);        // layer-0 edge update only
    addT(e_W0 + 256 * 128, wt_eac + 16384, 128, 128);
    addT(e_W0 + 128 * 128, wt_eb,          128, 128);
    addT(e_W1, wt_e1, 128, 128);
    addT(e_W2, wt_e2, 128, 128);
    tda.total = toff;
    k_transpose_all<<<(toff + 255) / 256, 256, 0, stream>>>(tda);

    const int n4a = NNODES * 128 / 4, n4b = E_ * 128 / 4;
    k_cvt2<<<(n4a + n4b + 255) / 256, 256, 0, stream>>>(x, nodes, n4a, eat0, edgec, n4b);

    // CSR build (once — edge_index constant across layers)
    hipMemsetAsync(deg, 0, NNODES * sizeof(int), stream);
    k_deg<<<E_ / 256, 256, 0, stream>>>(ei, deg);
    k_scan<<<1, 1024, 0, stream>>>(deg, off);
    hipMemcpyAsync(cur, off, NNODES * sizeof(int), hipMemcpyDeviceToDevice, stream);
    k_bucket<<<E_ / 256, 256, 0, stream>>>(ei, cur, elist);

    const dim3 gE(E_ / 64, 1), gPQ(NNODES / 64, 2), gN64(NNODES / 64, 1), gF0(NNODES / 128, 4);

    for (int l = 0; l < L_; ++l) {
        // --- message MLP: bf16 PQ pre-pass over nodes, then factorized fused chain ---
        pq_gemm<<<gPQ, 256, 0, stream>>>(nodes, wt_mac[l], msg_b0 + l * 128, PQb);
        fused_mlp3<false><<<gE, 256, 0, stream>>>(edgec, PQb, ei,
            wt_mb[l], wt_m1[l], wt_m2[l],
            msg_b1 + l * 128, msg_b2 + l * 128, nullptr, nullptr, tmpA);
        k_aggln<<<NNODES / 4, 256, 0, stream>>>(tmpA, off, elist, nodes,
            n0g + l * 128, n0b + l * 128, nodes);
        // --- feedforward + LN ---
        mlp_gemm<128, 128, 512, true ><<<gF0, 256, 0, stream>>>(nodes, wt_f0[l], ff_b0 + l * 512, ffh);
        mlp_gemm<64,  512, 128, false><<<gN64, 256, 0, stream>>>(ffh, wt_f1[l], ff_b1 + l * 128, ffo);
        if (l == L_ - 1) {
            k_ln<true ><<<NNODES / 4, 256, 0, stream>>>(nodes, ffo, n1g + l * 128, n1b + l * 128, d_out);
        } else {
            k_ln<false><<<NNODES / 4, 256, 0, stream>>>(nodes, ffo, n1g + l * 128, n1b + l * 128, nodes);
        }
        // --- edge update (only layer 0; layer-1's is dead code) ---
        if (l == 0) {
            pq_gemm<<<gPQ, 256, 0, stream>>>(nodes, wt_eac, e_b0, PQb);
            fused_mlp3<true><<<gE, 256, 0, stream>>>(edgec, PQb, ei,
                wt_eb, wt_e1, wt_e2, e_b1, e_b2, eng, enb, edgec);
        }
    }
}

// Round 12
// 453.014 us; speedup vs baseline: 1.9388x; 1.0530x over previous
//
#include <hip/hip_runtime.h>

#define E_      262144
#define NNODES  32768
#define L_      2

typedef __attribute__((ext_vector_type(8))) short  bf16x8;
typedef __attribute__((ext_vector_type(4))) float  f32x4;

typedef __attribute__((address_space(1))) const unsigned int gu32;
typedef __attribute__((address_space(3))) unsigned int       lu32;

__device__ __forceinline__ void gl16(const void* g, void* l) {
    // async global->LDS, 16B/lane; LDS dest = wave-uniform base + lane*16
    __builtin_amdgcn_global_load_lds((gu32*)g, (lu32*)l, 16, 0, 0);
}

__device__ __forceinline__ float bf2f(unsigned short u) {
    union { unsigned int i; float f; } v; v.i = ((unsigned int)u) << 16; return v.f;
}
__device__ __forceinline__ unsigned short f2bf(float f) {
    union { float f; unsigned int i; } v; v.f = f;
    unsigned int r = v.i + 0x7FFFu + ((v.i >> 16) & 1u);   // round-nearest-even
    return (unsigned short)(r >> 16);
}

// combined fp32->bf16 for nodes + edge_attr
__global__ __launch_bounds__(256)
void k_cvt2(const float* __restrict__ a, unsigned short* __restrict__ oa, int n4a,
            const float* __restrict__ b, unsigned short* __restrict__ ob, int n4b)
{
    int i = blockIdx.x * 256 + threadIdx.x;
    if (i < n4a) {
        float4 v = reinterpret_cast<const float4*>(a)[i];
        ushort4 o; o.x = f2bf(v.x); o.y = f2bf(v.y); o.z = f2bf(v.z); o.w = f2bf(v.w);
        reinterpret_cast<ushort4*>(oa)[i] = o;
    } else if (i < n4a + n4b) {
        int j = i - n4a;
        float4 v = reinterpret_cast<const float4*>(b)[j];
        ushort4 o; o.x = f2bf(v.x); o.y = f2bf(v.y); o.z = f2bf(v.z); o.w = f2bf(v.w);
        reinterpret_cast<ushort4*>(ob)[j] = o;
    }
}

// batched weight transpose: 13 matrices in one dispatch. [K][N] fp32 -> [N][K] bf16
struct TD  { const float* s; unsigned short* d; int off; int K; int nsh; };
struct TDA { TD v[13]; int total; };

__global__ __launch_bounds__(256)
void k_transpose_all(TDA t)
{
    int idx = blockIdx.x * 256 + threadIdx.x;
    if (idx >= t.total) return;
    int j = 0;
#pragma unroll
    for (int m = 1; m < 13; ++m) if (idx >= t.v[m].off) j = m;
    const TD& td = t.v[j];
    int local = idx - td.off;
    int k = local >> td.nsh;
    int n = local & ((1 << td.nsh) - 1);
    td.d[(size_t)n * td.K + k] = f2bf(td.s[local]);
}

// ---------------------------------------------------------------------------
// FUSED 3-stage edge MLP, BM=64 (R6-proven structure: stage->sync->mma->sync,
// K-chunk 64, 40KB LDS -> 4 blocks/CU, launch_bounds(256,4)):
//   h1 = relu(concat(nodes[src],eattr,nodes[dst]) @ W0 + b0)  (6 ksteps)
//   h2 = relu(h1 @ W1 + b1)  (2 ksteps);  m = h2 @ W2 + b2  (2 ksteps)
//   LNEPI=0: out[e]=m;  LNEPI=1: out[e]=LN(eattr[e]+m)*g+b
// ---------------------------------------------------------------------------
template<bool LNEPI>
__global__ __launch_bounds__(256, 4)
void fused_mlp3(const unsigned short* __restrict__ nodes,   // [NNODES][128]
                const unsigned short* __restrict__ eattr,   // [E][128]
                const int*            __restrict__ ei,      // [2][E]
                const unsigned short* __restrict__ W0T,     // [128][384]
                const unsigned short* __restrict__ W1T,     // [128][128]
                const unsigned short* __restrict__ W2T,     // [128][128]
                const float* __restrict__ b0, const float* __restrict__ b1,
                const float* __restrict__ b2,
                const float* __restrict__ g,  const float* __restrict__ bb,
                unsigned short* __restrict__ out)           // [E][128]
{
    __shared__ unsigned short S0[64 * 64];     //  8KB A-stage
    __shared__ unsigned short SB[128 * 64];    // 16KB W-stage (later LN scratch)
    __shared__ unsigned short H [64 * 128];    // 16KB h1 then h2

    const int tid  = threadIdx.x;
    const int lane = tid & 63;
    const int w    = tid >> 6;
    const int wr   = w >> 1, wc = w & 1;
    const int m0   = blockIdx.x * 64;

    const int lrow = lane >> 3;                   // 0..7 row within an 8-row issue
    const int soff = ((lane & 7) ^ lrow) * 8;     // inverse-swizzled 16B slot (elems)

    char* S0c = (char*)S0;
    char* SBc = (char*)SB;
    char* Hc  = (char*)H;

    // gather pointers: 2 issues of 8 rows per wave => 64 rows
    const unsigned short *pS[2], *pD[2], *pE[2];
#pragma unroll
    for (int i = 0; i < 2; ++i) {
        int r = w * 16 + i * 8 + lrow;
        int e = m0 + r;
        pS[i] = nodes + (size_t)ei[e]      * 128 + soff;
        pD[i] = nodes + (size_t)ei[E_ + e] * 128 + soff;
        pE[i] = eattr + (size_t)e          * 128 + soff;
    }

    f32x4 acc[2][4];
    auto zacc = [&]() {
#pragma unroll
        for (int m = 0; m < 2; ++m)
#pragma unroll
            for (int n = 0; n < 4; ++n) acc[m][n] = (f32x4){0.f, 0.f, 0.f, 0.f};
    };

    // ---- MFMA tile step: A from LDS (row stride abytes), B from SB ----
    auto mma = [&](const char* Ab, int abytes, int kbase) {
#pragma unroll
        for (int ks = 0; ks < 2; ++ks) {
            const int kb = (kbase + ks * 32) * 2 + (lane >> 4) * 16;
            bf16x8 a[2], b[4];
#pragma unroll
            for (int m = 0; m < 2; ++m) {
                int row = wr * 32 + m * 16 + (lane & 15);
                a[m] = *reinterpret_cast<const bf16x8*>(Ab + row * abytes + (kb ^ ((row & 7) << 4)));
            }
            const int kbb = ks * 64 + (lane >> 4) * 16;
#pragma unroll
            for (int n = 0; n < 4; ++n) {
                int row = wc * 64 + n * 16 + (lane & 15);
                b[n] = *reinterpret_cast<const bf16x8*>(SBc + row * 128 + (kbb ^ ((row & 7) << 4)));
            }
#pragma unroll
            for (int m = 0; m < 2; ++m)
#pragma unroll
                for (int n = 0; n < 4; ++n)
                    acc[m][n] = __builtin_amdgcn_mfma_f32_16x16x32_bf16(a[m], b[n], acc[m][n], 0, 0, 0);
        }
    };

    // ---- write activated acc -> H [64][128] bf16, swizzled slots ----
    auto towrite = [&](const float* bias) {
#pragma unroll
        for (int n = 0; n < 4; ++n) {
            int cg = wc * 64 + n * 16 + (lane & 15);
            float bi = bias[cg];
#pragma unroll
            for (int m = 0; m < 2; ++m) {
#pragma unroll
                for (int j = 0; j < 4; ++j) {
                    int rg = wr * 32 + m * 16 + (lane >> 4) * 4 + j;
                    float v = fmaxf(acc[m][n][j] + bi, 0.f);
                    *(unsigned short*)(Hc + rg * 256 + ((2 * cg) ^ ((rg & 7) << 4))) = f2bf(v);
                }
            }
        }
    };

    // ================= phase 1: h1 = relu(X @ W0 + b0), K=384 =================
    zacc();
    for (int k0 = 0; k0 < 384; k0 += 64) {
#pragma unroll
        for (int i = 0; i < 2; ++i) {
            const unsigned short* pa = (k0 < 128 ? pS[i] : (k0 < 256 ? pE[i] : pD[i])) + (k0 & 64);
            gl16(pa, S0c + (w * 16 + i * 8) * 128);
        }
#pragma unroll
        for (int i = 0; i < 4; ++i)
            gl16(W0T + (size_t)(w * 32 + i * 8 + lrow) * 384 + k0 + soff,
                 SBc + (w * 32 + i * 8) * 128);
        __syncthreads();
        mma(S0c, 128, 0);
        __syncthreads();
    }
    towrite(b0);
    // ================= phase 2: h2 = relu(h1 @ W1 + b1), K=128 ================
    zacc();
#pragma unroll
    for (int k0 = 0; k0 < 128; k0 += 64) {
#pragma unroll
        for (int i = 0; i < 4; ++i)
            gl16(W1T + (size_t)(w * 32 + i * 8 + lrow) * 128 + k0 + soff,
                 SBc + (w * 32 + i * 8) * 128);
        __syncthreads();        // h1 writes + W1 chunk visible
        mma(Hc, 256, k0);
        __syncthreads();
    }
    towrite(b1);                // h2 over h1: all h1 reads completed at loop-final barrier
    // ================= phase 3: m = h2 @ W2 + b2, K=128 =======================
    zacc();
#pragma unroll
    for (int k0 = 0; k0 < 128; k0 += 64) {
#pragma unroll
        for (int i = 0; i < 4; ++i)
            gl16(W2T + (size_t)(w * 32 + i * 8 + lrow) * 128 + k0 + soff,
                 SBc + (w * 32 + i * 8) * 128);
        __syncthreads();        // h2 writes + W2 chunk visible
        mma(Hc, 256, k0);
        __syncthreads();
    }

    // ================= epilogue =================
    if (!LNEPI) {
#pragma unroll
        for (int n = 0; n < 4; ++n) {
            int cg = wc * 64 + n * 16 + (lane & 15);
            float bi = b2[cg];
#pragma unroll
            for (int m = 0; m < 2; ++m) {
                int rg = m0 + wr * 32 + m * 16 + (lane >> 4) * 4;
                unsigned short* cp = out + (size_t)rg * 128 + cg;
#pragma unroll
                for (int j = 0; j < 4; ++j)
                    cp[(size_t)j * 128] = f2bf(acc[m][n][j] + bi);
            }
        }
    } else {
        // residual + LayerNorm fused. vals = m + b2 + eattr.
#pragma unroll
        for (int n = 0; n < 4; ++n) {
            int cg = wc * 64 + n * 16 + (lane & 15);
            float bi = b2[cg];
#pragma unroll
            for (int m = 0; m < 2; ++m) {
#pragma unroll
                for (int j = 0; j < 4; ++j) {
                    int rg = m0 + wr * 32 + m * 16 + (lane >> 4) * 4 + j;
                    acc[m][n][j] += bi + bf2f(eattr[(size_t)rg * 128 + cg]);
                }
            }
        }
        float* ps = (float*)SBc;          // [2][64] row sums   (SB dead)
        float* pq = ps + 128;             // [2][64] row sumsq
#pragma unroll
        for (int m = 0; m < 2; ++m) {
#pragma unroll
            for (int j = 0; j < 4; ++j) {
                float s = 0.f, q = 0.f;
#pragma unroll
                for (int n = 0; n < 4; ++n) {
                    float v = acc[m][n][j];
                    s += v; q += v * v;
                }
#pragma unroll
                for (int msk = 1; msk < 16; msk <<= 1) {
                    s += __shfl_xor(s, msk);
                    q += __shfl_xor(q, msk);
                }
                if ((lane & 15) == 0) {
                    int rl = wr * 32 + m * 16 + (lane >> 4) * 4 + j;
                    ps[wc * 64 + rl] = s;
                    pq[wc * 64 + rl] = q;
                }
            }
        }
        __syncthreads();
#pragma unroll
        for (int m = 0; m < 2; ++m) {
#pragma unroll
            for (int j = 0; j < 4; ++j) {
                int rl = wr * 32 + m * 16 + (lane >> 4) * 4 + j;
                float S = ps[rl] + ps[64 + rl];
                float Q = pq[rl] + pq[64 + rl];
                float mean = S * (1.f / 128.f);
                float var  = Q * (1.f / 128.f) - mean * mean;
                float rs   = rsqrtf(var + 1e-5f);
                int rg = m0 + rl;
#pragma unroll
                for (int n = 0; n < 4; ++n) {
                    int cg = wc * 64 + n * 16 + (lane & 15);
                    out[(size_t)rg * 128 + cg] =
                        f2bf((acc[m][n][j] - mean) * rs * g[cg] + bb[cg]);
                }
            }
        }
    }
}

// ---------------------------------------------------------------------------
// FF first GEMM: C = relu(A @ W0 + b0), BM=128 tile  [R6 structure]
// ---------------------------------------------------------------------------
template<int BM, int K, int NTOT, bool RELU>
__global__ __launch_bounds__(256)
void mlp_gemm(const unsigned short* __restrict__ Abase,
              const unsigned short* __restrict__ WT,      // [NTOT][K] bf16
              const float*          __restrict__ bias,    // [NTOT] fp32
              unsigned short*       __restrict__ C)       // [M][NTOT] bf16
{
    constexpr int MI = BM / 32;
    __shared__ unsigned short Alds[BM * 64];
    __shared__ unsigned short Blds[128 * 64];

    const int tid  = threadIdx.x;
    const int lane = tid & 63;
    const int w    = tid >> 6;
    const int wr   = w >> 1, wc = w & 1;
    const int m0   = blockIdx.x * BM;
    const int n0   = blockIdx.y * 128;

    const int lrow = lane >> 3;
    const int soff = ((lane & 7) ^ lrow) * 8;

    const unsigned short *pS[MI], *pB[4];
#pragma unroll
    for (int i = 0; i < MI; ++i)
        pS[i] = Abase + (size_t)(m0 + w * (BM / 4) + i * 8 + lrow) * K + soff;
#pragma unroll
    for (int i = 0; i < 4; ++i)
        pB[i] = WT + (size_t)(n0 + w * 32 + i * 8 + lrow) * K + soff;

    f32x4 acc[MI][4];
#pragma unroll
    for (int m = 0; m < MI; ++m)
#pragma unroll
        for (int n = 0; n < 4; ++n) acc[m][n] = (f32x4){0.f, 0.f, 0.f, 0.f};

#pragma unroll
    for (int k0 = 0; k0 < K; k0 += 64) {
#pragma unroll
        for (int i = 0; i < MI; ++i)
            gl16(pS[i] + k0, Alds + (w * (BM / 4) + i * 8) * 64);
#pragma unroll
        for (int i = 0; i < 4; ++i)
            gl16(pB[i] + k0, Blds + (w * 32 + i * 8) * 64);
        __syncthreads();

#pragma unroll
        for (int ks = 0; ks < 2; ++ks) {
            const int kb = ks * 64 + (lane >> 4) * 16;
            bf16x8 a[MI], b[4];
#pragma unroll
            for (int m = 0; m < MI; ++m) {
                int row = wr * (BM / 2) + m * 16 + (lane & 15);
                a[m] = *reinterpret_cast<const bf16x8*>(
                    (const char*)Alds + row * 128 + (kb ^ ((row & 7) << 4)));
            }
#pragma unroll
            for (int n = 0; n < 4; ++n) {
                int row = wc * 64 + n * 16 + (lane & 15);
                b[n] = *reinterpret_cast<const bf16x8*>(
                    (const char*)Blds + row * 128 + (kb ^ ((row & 7) << 4)));
            }
#pragma unroll
            for (int m = 0; m < MI; ++m)
#pragma unroll
                for (int n = 0; n < 4; ++n)
                    acc[m][n] = __builtin_amdgcn_mfma_f32_16x16x32_bf16(a[m], b[n], acc[m][n], 0, 0, 0);
        }
        __syncthreads();
    }

#pragma unroll
    for (int n = 0; n < 4; ++n) {
        int colg = n0 + wc * 64 + n * 16 + (lane & 15);
        float bi = bias[colg];
#pragma unroll
        for (int m = 0; m < MI; ++m) {
            int rowg = m0 + wr * (BM / 2) + m * 16 + (lane >> 4) * 4;
            unsigned short* cp = C + (size_t)rowg * NTOT + colg;
#pragma unroll
            for (int j = 0; j < 4; ++j) {
                float r = acc[m][n][j] + bi;
                if (RELU) r = fmaxf(r, 0.f);
                cp[(size_t)j * NTOT] = f2bf(r);
            }
        }
    }
}

// ---------------------------------------------------------------------------
// FF second GEMM + fused residual + LayerNorm: per block 64 rows x 128 cols
// (full rows -> LN reduction is block-local, Blds reused as scratch).
//   y = LN( resid + (A @ W1 + b1) ) * g + bb
// F32OUT: write fp32 (final output) else bf16 (nodes in-place; each element
// read-then-written by the same thread -> safe).
// ---------------------------------------------------------------------------
template<bool F32OUT>
__global__ __launch_bounds__(256)
void ff1_ln(const unsigned short* __restrict__ Abase,   // ffh [M][512]
            const unsigned short* __restrict__ WT,      // [128][512]
            const float* __restrict__ bias,             // [128]
            const unsigned short* __restrict__ resid,   // nodes [M][128]
            const float* __restrict__ g, const float* __restrict__ bb,
            void* __restrict__ outp)
{
    constexpr int K = 512;
    __shared__ unsigned short Alds[64 * 64];    //  8KB
    __shared__ unsigned short Blds[128 * 64];   // 16KB (LN scratch after loop)

    const int tid  = threadIdx.x;
    const int lane = tid & 63;
    const int w    = tid >> 6;
    const int wr   = w >> 1, wc = w & 1;
    const int m0   = blockIdx.x * 64;

    const int lrow = lane >> 3;
    const int soff = ((lane & 7) ^ lrow) * 8;

    const unsigned short *pS[2], *pB[4];
#pragma unroll
    for (int i = 0; i < 2; ++i)
        pS[i] = Abase + (size_t)(m0 + w * 16 + i * 8 + lrow) * K + soff;
#pragma unroll
    for (int i = 0; i < 4; ++i)
        pB[i] = WT + (size_t)(w * 32 + i * 8 + lrow) * K + soff;

    f32x4 acc[2][4];
#pragma unroll
    for (int m = 0; m < 2; ++m)
#pragma unroll
        for (int n = 0; n < 4; ++n) acc[m][n] = (f32x4){0.f, 0.f, 0.f, 0.f};

#pragma unroll
    for (int k0 = 0; k0 < K; k0 += 64) {
#pragma unroll
        for (int i = 0; i < 2; ++i)
            gl16(pS[i] + k0, Alds + (w * 16 + i * 8) * 64);
#pragma unroll
        for (int i = 0; i < 4; ++i)
            gl16(pB[i] + k0, Blds + (w * 32 + i * 8) * 64);
        __syncthreads();

#pragma unroll
        for (int ks = 0; ks < 2; ++ks) {
            const int kb = ks * 64 + (lane >> 4) * 16;
            bf16x8 a[2], b[4];
#pragma unroll
            for (int m = 0; m < 2; ++m) {
                int row = wr * 32 + m * 16 + (lane & 15);
                a[m] = *reinterpret_cast<const bf16x8*>(
                    (const char*)Alds + row * 128 + (kb ^ ((row & 7) << 4)));
            }
#pragma unroll
            for (int n = 0; n < 4; ++n) {
                int row = wc * 64 + n * 16 + (lane & 15);
                b[n] = *reinterpret_cast<const bf16x8*>(
                    (const char*)Blds + row * 128 + (kb ^ ((row & 7) << 4)));
            }
#pragma unroll
            for (int m = 0; m < 2; ++m)
#pragma unroll
                for (int n = 0; n < 4; ++n)
                    acc[m][n] = __builtin_amdgcn_mfma_f32_16x16x32_bf16(a[m], b[n], acc[m][n], 0, 0, 0);
        }
        __syncthreads();
    }

    // ---- residual + bias into acc ----
#pragma unroll
    for (int n = 0; n < 4; ++n) {
        int cg = wc * 64 + n * 16 + (lane & 15);
        float bi = bias[cg];
#pragma unroll
        for (int m = 0; m < 2; ++m) {
#pragma unroll
            for (int j = 0; j < 4; ++j) {
                int rg = m0 + wr * 32 + m * 16 + (lane >> 4) * 4 + j;
                acc[m][n][j] += bi + bf2f(resid[(size_t)rg * 128 + cg]);
            }
        }
    }
    // ---- LN row reduction (Blds scratch) ----
    float* ps = (float*)Blds;         // [2][64] row sums
    float* pq = ps + 128;             // [2][64] row sumsq
#pragma unroll
    for (int m = 0; m < 2; ++m) {
#pragma unroll
        for (int j = 0; j < 4; ++j) {
            float s = 0.f, q = 0.f;
#pragma unroll
            for (int n = 0; n < 4; ++n) {
                float v = acc[m][n][j];
                s += v; q += v * v;
            }
#pragma unroll
            for (int msk = 1; msk < 16; msk <<= 1) {
                s += __shfl_xor(s, msk);
                q += __shfl_xor(q, msk);
            }
            if ((lane & 15) == 0) {
                int rl = wr * 32 + m * 16 + (lane >> 4) * 4 + j;
                ps[wc * 64 + rl] = s;
                pq[wc * 64 + rl] = q;
            }
        }
    }
    __syncthreads();
#pragma unroll
    for (int m = 0; m < 2; ++m) {
#pragma unroll
        for (int j = 0; j < 4; ++j) {
            int rl = wr * 32 + m * 16 + (lane >> 4) * 4 + j;
            float S = ps[rl] + ps[64 + rl];
            float Q = pq[rl] + pq[64 + rl];
            float mean = S * (1.f / 128.f);
            float var  = Q * (1.f / 128.f) - mean * mean;
            float rs   = rsqrtf(var + 1e-5f);
            int rg = m0 + rl;
#pragma unroll
            for (int n = 0; n < 4; ++n) {
                int cg = wc * 64 + n * 16 + (lane & 15);
                float y = (acc[m][n][j] - mean) * rs * g[cg] + bb[cg];
                if (F32OUT) ((float*)outp)[(size_t)rg * 128 + cg] = y;
                else ((unsigned short*)outp)[(size_t)rg * 128 + cg] = f2bf(y);
            }
        }
    }
}

__global__ __launch_bounds__(256)
void k_deg(const int* __restrict__ ei, int* __restrict__ deg)
{
    int e = blockIdx.x * 256 + threadIdx.x;
    atomicAdd(&deg[ei[E_ + e]], 1);
}

// exclusive scan of deg[32768] -> off[32769]
__global__ __launch_bounds__(1024)
void k_scan(const int* __restrict__ deg, int* __restrict__ off)
{
    __shared__ int part[1024];
    const int t = threadIdx.x;
    const int base = t * 32;
    int loc[32];
    int s = 0;
#pragma unroll
    for (int i = 0; i < 32; ++i) { loc[i] = s; s += deg[base + i]; }
    part[t] = s;
    __syncthreads();
    for (int d = 1; d < 1024; d <<= 1) {
        int v = (t >= d) ? part[t - d] : 0;
        __syncthreads();
        part[t] += v;
        __syncthreads();
    }
    const int pre = (t == 0) ? 0 : part[t - 1];
#pragma unroll
    for (int i = 0; i < 32; ++i) off[base + i] = pre + loc[i];
    if (t == 1023) off[NNODES] = pre + s;
}

__global__ __launch_bounds__(256)
void k_bucket(const int* __restrict__ ei, int* __restrict__ cursor, int* __restrict__ elist)
{
    int e = blockIdx.x * 256 + threadIdx.x;
    int d = ei[E_ + e];
    int pos = atomicAdd(&cursor[d], 1);
    elist[pos] = e;
}

// Fused: agg = mean_{e in CSR[v]} m[e];  out = LN(nodes_in[v] + agg).
__global__ __launch_bounds__(256)
void k_aggln(const unsigned short* __restrict__ m,
             const int* __restrict__ off, const int* __restrict__ elist,
             const unsigned short* __restrict__ nodes_in,
             const float* __restrict__ g, const float* __restrict__ bb,
             unsigned short* __restrict__ nodes_out)
{
    const int v    = blockIdx.x * 4 + (threadIdx.x >> 6);
    const int lane = threadIdx.x & 63;
    const int c    = lane * 2;
    const int beg  = off[v], end = off[v + 1];

    float a0 = 0.f, a1 = 0.f;
    for (int i = beg; i < end; ++i) {
        int e = elist[i];
        unsigned int u = *reinterpret_cast<const unsigned int*>(m + (size_t)e * 128 + c);
        a0 += bf2f((unsigned short)(u & 0xffffu));
        a1 += bf2f((unsigned short)(u >> 16));
    }
    const float inv = 1.f / fmaxf((float)(end - beg), 1.f);
    const size_t o = (size_t)v * 128 + c;
    float x0 = bf2f(nodes_in[o])     + a0 * inv;
    float x1 = bf2f(nodes_in[o + 1]) + a1 * inv;

    float s = x0 + x1, sq = x0 * x0 + x1 * x1;
#pragma unroll
    for (int mm = 1; mm < 64; mm <<= 1) { s += __shfl_xor(s, mm); sq += __shfl_xor(sq, mm); }
    float mean = s * (1.f / 128.f);
    float var  = sq * (1.f / 128.f) - mean * mean;
    float rs   = rsqrtf(var + 1e-5f);
    nodes_out[o]     = f2bf((x0 - mean) * rs * g[c]     + bb[c]);
    nodes_out[o + 1] = f2bf((x1 - mean) * rs * g[c + 1] + bb[c + 1]);
}

// ---------------------------------------------------------------------------
extern "C" void kernel_launch(void* const* d_in, const int* in_sizes, int n_in,
                              void* d_out, int out_size, void* d_ws, size_t ws_size,
                              hipStream_t stream)
{
    const float* x      = (const float*)d_in[0];
    const int*   ei     = (const int*)d_in[1];
    const float* eat0   = (const float*)d_in[2];
    const float* msg_W0 = (const float*)d_in[3];
    const float* msg_b0 = (const float*)d_in[4];
    const float* msg_W1 = (const float*)d_in[5];
    const float* msg_b1 = (const float*)d_in[6];
    const float* msg_W2 = (const float*)d_in[7];
    const float* msg_b2 = (const float*)d_in[8];
    const float* n0g    = (const float*)d_in[9];
    const float* n0b    = (const float*)d_in[10];
    const float* ff_W0  = (const float*)d_in[11];
    const float* ff_b0  = (const float*)d_in[12];
    const float* ff_W1  = (const float*)d_in[13];
    const float* ff_b1  = (const float*)d_in[14];
    const float* n1g    = (const float*)d_in[15];
    const float* n1b    = (const float*)d_in[16];
    const float* e_W0   = (const float*)d_in[17];
    const float* e_b0   = (const float*)d_in[18];
    const float* e_W1   = (const float*)d_in[19];
    const float* e_b1   = (const float*)d_in[20];
    const float* e_W2   = (const float*)d_in[21];
    const float* e_b2   = (const float*)d_in[22];
    const float* eng    = (const float*)d_in[23];
    const float* enb    = (const float*)d_in[24];

    char* ws = (char*)d_ws;
    const size_t MB = (size_t)1 << 20;
    unsigned short* nodes = (unsigned short*)(ws);                 // 8 MB bf16
    unsigned short* edgec = (unsigned short*)(ws + 8 * MB);        // 64 MB bf16
    unsigned short* tmpA  = (unsigned short*)(ws + 72 * MB);       // 64 MB (msg out m)
    unsigned short* ffh   = (unsigned short*)(ws + 136 * MB);      // 32 MB (FF hidden)
    unsigned short* wt    = (unsigned short*)(ws + 200 * MB);      // ~1 MB bf16
    int*            deg   = (int*)(ws + 202 * MB);                 // 128 KB
    int*            off   = (int*)(ws + 202 * MB + 256 * 1024);    // 128 KB + 4
    int*            cur   = (int*)(ws + 202 * MB + 512 * 1024);    // 128 KB
    int*            elist = (int*)(ws + 202 * MB + 768 * 1024);    // 1 MB

    // weight transpose targets (bf16 [N][K])
    unsigned short* p = wt;
    unsigned short *wt_m0[L_], *wt_m1[L_], *wt_m2[L_], *wt_f0[L_], *wt_f1[L_];
    for (int l = 0; l < L_; ++l) {
        wt_m0[l] = p; p += 384 * 128;
        wt_m1[l] = p; p += 128 * 128;
        wt_m2[l] = p; p += 128 * 128;
        wt_f0[l] = p; p += 128 * 512;
        wt_f1[l] = p; p += 512 * 128;
    }
    unsigned short* wt_e0 = p; p += 384 * 128;
    unsigned short* wt_e1 = p; p += 128 * 128;
    unsigned short* wt_e2 = p; p += 128 * 128;

    TDA tda; int toff = 0, ti = 0;
    auto addT = [&](const float* s, unsigned short* d, int K, int N) {
        tda.v[ti++] = TD{s, d, toff, K, (N == 512 ? 9 : 7)};
        toff += K * N;
    };
    for (int l = 0; l < L_; ++l) {
        addT(msg_W0 + l * 384 * 128, wt_m0[l], 384, 128);
        addT(msg_W1 + l * 128 * 128, wt_m1[l], 128, 128);
        addT(msg_W2 + l * 128 * 128, wt_m2[l], 128, 128);
        addT(ff_W0  + l * 128 * 512, wt_f0[l], 128, 512);
        addT(ff_W1  + l * 512 * 128, wt_f1[l], 512, 128);
    }
    addT(e_W0, wt_e0, 384, 128);   // layer-0 edge update only (layer-1's is dead code)
    addT(e_W1, wt_e1, 128, 128);
    addT(e_W2, wt_e2, 128, 128);
    tda.total = toff;
    k_transpose_all<<<(toff + 255) / 256, 256, 0, stream>>>(tda);

    const int n4a = NNODES * 128 / 4, n4b = E_ * 128 / 4;
    k_cvt2<<<(n4a + n4b + 255) / 256, 256, 0, stream>>>(x, nodes, n4a, eat0, edgec, n4b);

    // CSR build (once — edge_index constant across layers)
    hipMemsetAsync(deg, 0, NNODES * sizeof(int), stream);
    k_deg<<<E_ / 256, 256, 0, stream>>>(ei, deg);
    k_scan<<<1, 1024, 0, stream>>>(deg, off);
    hipMemcpyAsync(cur, off, NNODES * sizeof(int), hipMemcpyDeviceToDevice, stream);
    k_bucket<<<E_ / 256, 256, 0, stream>>>(ei, cur, elist);

    const dim3 gE(E_ / 64, 1), gN64(NNODES / 64, 1), gF0(NNODES / 128, 4);

    for (int l = 0; l < L_; ++l) {
        // --- fused message MLP (3 GEMMs in one kernel) -> m ---
        fused_mlp3<false><<<gE, 256, 0, stream>>>(nodes, edgec, ei,
            wt_m0[l], wt_m1[l], wt_m2[l],
            msg_b0 + l * 128, msg_b1 + l * 128, msg_b2 + l * 128,
            nullptr, nullptr, tmpA);
        k_aggln<<<NNODES / 4, 256, 0, stream>>>(tmpA, off, elist, nodes,
            n0g + l * 128, n0b + l * 128, nodes);
        // --- feedforward: GEMM1, then GEMM2 fused with residual+LN ---
        mlp_gemm<128, 128, 512, true><<<gF0, 256, 0, stream>>>(nodes, wt_f0[l], ff_b0 + l * 512, ffh);
        if (l == L_ - 1) {
            ff1_ln<true ><<<gN64, 256, 0, stream>>>(ffh, wt_f1[l], ff_b1 + l * 128,
                nodes, n1g + l * 128, n1b + l * 128, d_out);
        } else {
            ff1_ln<false><<<gN64, 256, 0, stream>>>(ffh, wt_f1[l], ff_b1 + l * 128,
                nodes, n1g + l * 128, n1b + l * 128, nodes);
        }
        // --- fused edge update incl. residual+LN (only layer 0; layer-1's is dead) ---
        if (l == 0) {
            fused_mlp3<true><<<gE, 256, 0, stream>>>(nodes, edgec, ei,
                wt_e0, wt_e1, wt_e2, e_b0, e_b1, e_b2, eng, enb, edgec);
        }
    }
}